// Round 6
// baseline (1376.492 us; speedup 1.0000x reference)
//
#include <hip/hip_runtime.h>
#include <hip/hip_bf16.h>

typedef unsigned short u16;
typedef unsigned int   u32;

// Problem constants: B=2, N=4, C=128, HEADS=8, P=4, H=W=96, TC=64, ITERS=3, HD=16
constexpr int kHW = 9216;       // 96*96
constexpr int kM  = 147456;     // 16*9216 (item-major image stride in floats; also B*HEADS*HW items)

__device__ __forceinline__ float gelu_f(float v){ return 0.5f*v*(1.0f+erff(v*0.70710678118654752f)); }
__device__ __forceinline__ float sigm_f(float v){ return 1.0f/(1.0f+expf(-v)); }

struct Bilin { int i00,i10,i01,i11; float w00,w10,w01,w11; };

__device__ __forceinline__ Bilin make_bilin(int x, int y, float ox, float oy){
  float gx = fmaf((float)x, 2.0f/95.0f, -1.0f);
  float gy = fmaf((float)y, 2.0f/95.0f, -1.0f);
  float sgx = fminf(fmaxf(gx+ox,-1.0f),1.0f);
  float sgy = fminf(fmaxf(gy+oy,-1.0f),1.0f);
  float ix = (sgx+1.0f)*0.5f*95.0f;
  float iy = (sgy+1.0f)*0.5f*95.0f;
  float x0f = floorf(ix), y0f = floorf(iy);
  float wx = ix-x0f, wy = iy-y0f;
  int x0 = min(max((int)x0f,0),95), y0 = min(max((int)y0f,0),95);
  int x1 = min(x0+1,95), y1 = min(y0+1,95);
  Bilin b;
  b.i00=(y0*96+x0)*16; b.i10=(y0*96+x1)*16; b.i01=(y1*96+x0)*16; b.i11=(y1*96+x1)*16;
  float iwx=1.0f-wx, iwy=1.0f-wy;
  b.w00=iwx*iwy; b.w10=wx*iwy; b.w01=iwx*wy; b.w11=wx*wy;
  return b;
}

__device__ __forceinline__ void sample16(const float* __restrict__ vp, const Bilin& bl, float* __restrict__ o){
  const float4* p00 = (const float4*)(vp + bl.i00);
  const float4* p10 = (const float4*)(vp + bl.i10);
  const float4* p01 = (const float4*)(vp + bl.i01);
  const float4* p11 = (const float4*)(vp + bl.i11);
  #pragma unroll
  for (int g = 0; g < 4; ++g){
    float4 a=p00[g], b=p10[g], c=p01[g], d=p11[g];
    o[g*4+0] = a.x*bl.w00 + b.x*bl.w10 + c.x*bl.w01 + d.x*bl.w11;
    o[g*4+1] = a.y*bl.w00 + b.y*bl.w10 + c.y*bl.w01 + d.y*bl.w11;
    o[g*4+2] = a.z*bl.w00 + b.z*bl.w10 + c.z*bl.w01 + d.z*bl.w11;
    o[g*4+3] = a.w*bl.w00 + b.w*bl.w10 + c.w*bl.w01 + d.w*bl.w11;
  }
}

// partial bilinear: 4 channels starting at ch0 (same per-channel FMA order as sample16)
__device__ __forceinline__ void sample4(const float* __restrict__ vp, const Bilin& bl, int ch0, float* __restrict__ o){
  float4 a = *(const float4*)(vp + bl.i00 + ch0);
  float4 b = *(const float4*)(vp + bl.i10 + ch0);
  float4 c = *(const float4*)(vp + bl.i01 + ch0);
  float4 d = *(const float4*)(vp + bl.i11 + ch0);
  o[0] = a.x*bl.w00 + b.x*bl.w10 + c.x*bl.w01 + d.x*bl.w11;
  o[1] = a.y*bl.w00 + b.y*bl.w10 + c.y*bl.w01 + d.y*bl.w11;
  o[2] = a.z*bl.w00 + b.z*bl.w10 + c.z*bl.w01 + d.z*bl.w11;
  o[3] = a.w*bl.w00 + b.w*bl.w10 + c.w*bl.w01 + d.w*bl.w11;
}

// ---------------- transpose the five (C,C) weight matrices into [c][o] f32 ----------------
__global__ __launch_bounds__(256) void prep_k(const float* __restrict__ qw, const float* __restrict__ vw,
    const float* __restrict__ pww, const float* __restrict__ o1w, const float* __restrict__ o2w,
    float* __restrict__ wt)
{
  const float* src = (blockIdx.y==0)?qw:(blockIdx.y==1)?vw:(blockIdx.y==2)?pww:(blockIdx.y==3)?o1w:o2w;
  float* d = wt + blockIdx.y*16384;
  int i = blockIdx.x*256 + threadIdx.x;
  int o = i & 127, c = i >> 7;
  d[i] = src[o*128 + c];
}

// ---------------- conv1x1 as register-tiled GEMM (unchanged from r5) ----------------
template<int ASRC, int EPI>
__global__ __launch_bounds__(256, 3) void gemm1x1_k(const float* __restrict__ inp,
    const float* __restrict__ wt, const float* __restrict__ bias,
    float* __restrict__ outf, const float* __restrict__ gate)
{
  __shared__ __align__(16) float a_s[16*132];
  __shared__ __align__(16) float b_s[16*132];
  const int tid = threadIdx.x;
  const int tx = tid & 15, ty = tid >> 4;
  const int img = blockIdx.y;
  const int px0 = blockIdx.x * 128;
  const int sr = tid >> 4;
  const int sc = (tid & 15) * 8;

  float acc[64];
  #pragma unroll
  for (int oj = 0; oj < 8; ++oj) {
    float bv = bias[tx*8+oj];
    #pragma unroll
    for (int pi = 0; pi < 8; ++pi) acc[pi*8+oj] = bv;
  }

  for (int kc = 0; kc < 8; ++kc) {
    const int k0 = kc*16;
    { const float4* g = (const float4*)(wt + (k0+sr)*128 + sc);
      float4 v0 = g[0], v1 = g[1];
      *(float4*)&b_s[sr*132+sc] = v0; *(float4*)&b_s[sr*132+sc+4] = v1; }
    if (ASRC == 0) {
      const float4* g = (const float4*)(inp + (size_t)(img*128 + k0 + sr)*kHW + px0 + sc);
      float4 v0 = g[0], v1 = g[1];
      *(float4*)&a_s[sr*132+sc] = v0; *(float4*)&a_s[sr*132+sc+4] = v1;
    } else {
      const int px = tid >> 1, hd0 = (tid & 1)*8;
      const float4* g = (const float4*)(inp + ((size_t)(img*8 + kc)*kHW + px0 + px)*16 + hd0);
      float4 v0 = g[0], v1 = g[1];
      a_s[(hd0+0)*132+px]=v0.x; a_s[(hd0+1)*132+px]=v0.y; a_s[(hd0+2)*132+px]=v0.z; a_s[(hd0+3)*132+px]=v0.w;
      a_s[(hd0+4)*132+px]=v1.x; a_s[(hd0+5)*132+px]=v1.y; a_s[(hd0+6)*132+px]=v1.z; a_s[(hd0+7)*132+px]=v1.w;
    }
    __syncthreads();
    #pragma unroll
    for (int k = 0; k < 16; ++k) {
      float4 b0 = *(const float4*)&b_s[k*132 + tx*8];
      float4 b1 = *(const float4*)&b_s[k*132 + tx*8 + 4];
      float4 a0 = *(const float4*)&a_s[k*132 + ty*8];
      float4 a1 = *(const float4*)&a_s[k*132 + ty*8 + 4];
      float av[8] = {a0.x,a0.y,a0.z,a0.w,a1.x,a1.y,a1.z,a1.w};
      float bv[8] = {b0.x,b0.y,b0.z,b0.w,b1.x,b1.y,b1.z,b1.w};
      #pragma unroll
      for (int pi = 0; pi < 8; ++pi)
        #pragma unroll
        for (int oj = 0; oj < 8; ++oj)
          acc[pi*8+oj] = fmaf(av[pi], bv[oj], acc[pi*8+oj]);
    }
    __syncthreads();
  }

  if (EPI == 0) {
    const int head = tx >> 1, hd0 = (tx & 1)*8;
    #pragma unroll
    for (int pi = 0; pi < 8; ++pi) {
      const int px = px0 + ty*8 + pi;
      float* dst = outf + ((size_t)(img*8 + head)*kHW + px)*16 + hd0;
      float4 t0 = {acc[pi*8+0],acc[pi*8+1],acc[pi*8+2],acc[pi*8+3]};
      float4 t1 = {acc[pi*8+4],acc[pi*8+5],acc[pi*8+6],acc[pi*8+7]};
      *(float4*)dst = t0; *(float4*)(dst+4) = t1;
    }
  } else {
    #pragma unroll
    for (int oj = 0; oj < 8; ++oj) {
      const int o = tx*8 + oj;
      float* dst = outf + (size_t)(img*128 + o)*kHW + px0 + ty*8;
      float v[8];
      #pragma unroll
      for (int pi = 0; pi < 8; ++pi) {
        float t = acc[pi*8+oj];
        v[pi] = (EPI == 1) ? gelu_f(t) : t * sigm_f(gate[o]);
      }
      float4 t0 = {v[0],v[1],v[2],v[3]};
      float4 t1 = {v[4],v[5],v[6],v[7]};
      *(float4*)dst = t0; *(float4*)(dst+4) = t1;
    }
  }
}

// ---------------- depthwise 7x7 + bias + exact gelu ----------------
__global__ __launch_bounds__(256) void dw_k(const float* __restrict__ q, const float* __restrict__ dww,
    const float* __restrict__ dwb, float* __restrict__ outf)
{
  int idx = blockIdx.x*256 + threadIdx.x;
  int px = idx % kHW;
  int bc = idx / kHW;
  int c = bc & 127;
  int x = px % 96, y = px / 96;
  float s = dwb[c];
  const float* qb = q + (size_t)bc*kHW;
  #pragma unroll
  for (int ky = 0; ky < 7; ++ky) {
    int yy = y + ky - 3;
    if (yy < 0 || yy > 95) continue;
    #pragma unroll
    for (int kx = 0; kx < 7; ++kx) {
      int xx = x + kx - 3;
      if (xx < 0 || xx > 95) continue;
      s = fmaf(qb[yy*96+xx], dww[c*49 + ky*7 + kx], s);
    }
  }
  outf[idx] = gelu_f(s);
}

// ---------------- time bias: (B,HEADS,N) ----------------
__global__ void tb_k(const float* __restrict__ te, const float* __restrict__ tw,
                     const float* __restrict__ tbias, float* __restrict__ tbb)
{
  int i = threadIdx.x;
  if (i >= 64) return;
  int b = i >> 5, h = (i >> 2) & 7, n = i & 3;
  float s = tbias[h];
  for (int tc = 0; tc < 64; ++tc) s = fmaf(te[(b*4+n)*64 + tc], tw[h*64+tc], s);
  tbb[(b*8+h)*4 + n] = s;
}

// ---------------- FUSED v2: 4 lanes per item (quad-parallel) ----------------
// 2304 blocks x 256 threads = 64 items/block x 4 lanes/item. 9216 waves total (4x r5).
// Quad lane lq owns channels/rows 4*lq..4*lq+3; exchanges via same-wave LDS (no barriers).
__global__ __launch_bounds__(256, 6) void fused_k(
    const float* __restrict__ qb, const float* __restrict__ vs,
    const float* __restrict__ netb, const float* __restrict__ relt,
    const float* __restrict__ wih, const float* __restrict__ whh,
    const float* __restrict__ bihp, const float* __restrict__ bhhp,
    const float* __restrict__ offw, const float* __restrict__ offbp,
    const float* __restrict__ aw, const float* __restrict__ abp,
    const float* __restrict__ tbb,
    float* __restrict__ outattn, float* __restrict__ entb)
{
  __shared__ __align__(16) float s_wih[48*20];   // rows padded 18->20 (pad=0)
  __shared__ __align__(16) float s_whh[48*16];
  __shared__ __align__(16) float s_offw[8*16];
  __shared__ __align__(16) float s_aw[4*16];
  __shared__ float s_bih[48], s_bhh[48], s_offb[8], s_ab[4];
  __shared__ __align__(16) float s_h[64*16];     // per-item h exchange
  __shared__ __align__(16) float s_xv[64*16];    // per-item sampled-x exchange
  const int tid = threadIdx.x;
  for (int i = tid; i < 960; i += 256){ int g = i/20, k = i%20; s_wih[i] = (k<18)? wih[g*18+k] : 0.0f; }
  for (int i = tid; i < 768; i += 256) s_whh[i] = whh[i];
  if (tid < 128) s_offw[tid] = offw[tid];
  if (tid < 64)  s_aw[tid]  = aw[tid];
  if (tid < 48){ s_bih[tid] = bihp[tid]; s_bhh[tid] = bhhp[tid]; }
  if (tid < 8)   s_offb[tid] = offbp[tid];
  if (tid < 4)   s_ab[tid]  = abp[tid];

  const int li = tid >> 2;           // item-in-block 0..63
  const int lq = tid & 3;            // lane-in-quad
  const int ch0 = lq*4;              // owned channel/row base
  // XCD swizzle: 2304 blocks = 16 bh-groups x 144. XCD x (round-robin heuristic) serves
  // bh {x, x+8} -> per-XCD v working set 2 bh x 4 n x 590 KB ~ 4.7 MB ~ L2.
  const int xcd = blockIdx.x & 7, slot = blockIdx.x >> 3;      // slot 0..287
  const int vblk = (xcd + 8*(slot/144))*144 + (slot%144);
  const int item = vblk*64 + li;
  const int yx = item % kHW; const int bh = item / kHW;
  const int b = bh >> 3, head = bh & 7;
  const int x = yx % 96, y = yx / 96;
  int nidx = 0;
  { float bv = fabsf(relt[b*4]);
    for (int n = 1; n < 4; ++n){ float a = fabsf(relt[b*4+n]); if (a < bv){ bv=a; nidx=n; } } }
  const float* vp = vs + (size_t)((b*4+nidx)*8 + head)*kM;

  // ---- correlation argmax: quad-split f64 dot + shuffle reduce ----
  float off_[8], attn_[4];
  {
    float4 qv4 = *(const float4*)(qb + (size_t)bh*kM + yx*16 + ch0);
    const int sdx[5] = {0,-1,1,0,0};   // SHIFTS entries are (dx,dy)
    const int sdy[5] = {0,0,0,-1,1};
    double bsc = 0.0; int best = 0;
    #pragma unroll
    for (int s5 = 0; s5 < 5; ++s5) {
      int sy = y - sdy[s5], sx = x - sdx[s5];
      double sc = 0.0;
      if (sy >= 0 && sy < 96 && sx >= 0 && sx < 96) {
        float4 tp4 = *(const float4*)(vp + (sy*96+sx)*16 + ch0);
        sc += (double)qv4.x*(double)tp4.x;
        sc += (double)qv4.y*(double)tp4.y;
        sc += (double)qv4.z*(double)tp4.z;
        sc += (double)qv4.w*(double)tp4.w;
      }
      sc += __shfl_xor(sc, 1);
      sc += __shfl_xor(sc, 2);
      if (s5 == 0) { bsc = sc; best = 0; }
      else if (sc > bsc) { bsc = sc; best = s5; }
    }
    const float STEP = 2.0f/96.0f;
    float ox = 0.f, oy = 0.f;        // reference swap: x-offset = dy*2/W, y-offset = dx*2/H
    if (best == 3) ox = -STEP; else if (best == 4) ox = STEP;
    if (best == 1) oy = -STEP; else if (best == 2) oy = STEP;
    #pragma unroll
    for (int p = 0; p < 4; ++p) { off_[2*p] = ox; off_[2*p+1] = oy; attn_[p] = 0.0f; }
  }

  __syncthreads();   // LDS weights ready (s_h/s_xv used only after this, same-wave per quad)

  // initial h: lane loads own quarter, exchange to full via LDS
  float h[16];
  {
    float4 mine = *(const float4*)(netb + (size_t)item*16 + ch0);
    *(float4*)&s_h[li*16 + ch0] = mine;
    #pragma unroll
    for (int g = 0; g < 4; ++g) {
      float4 t = *(const float4*)&s_h[li*16 + g*4];
      h[g*4]=t.x; h[g*4+1]=t.y; h[g*4+2]=t.z; h[g*4+3]=t.w;
    }
  }

  // ---- 3 GRU refinement iterations ----
  for (int it = 0; it < 3; ++it) {
    const float p0x = off_[0];
    const float p0y = off_[1];
    Bilin bl = make_bilin(x, y, p0x, p0y);
    float xv[20];
    {
      float mine[4];
      sample4(vp, bl, ch0, mine);
      *(float4*)&s_xv[li*16 + ch0] = *(float4*)mine;
      #pragma unroll
      for (int g = 0; g < 4; ++g) {
        float4 t = *(const float4*)&s_xv[li*16 + g*4];
        xv[g*4]=t.x; xv[g*4+1]=t.y; xv[g*4+2]=t.z; xv[g*4+3]=t.w;
      }
    }
    xv[16] = p0x; xv[17] = p0y; xv[18] = 0.f; xv[19] = 0.f;

    float hn[4];
    #pragma unroll
    for (int jj = 0; jj < 4; ++jj) {
      const int j = ch0 + jj;
      float g0 = s_bih[j], g1 = s_bih[16+j], g2 = s_bih[32+j];
      const float4* w0r = (const float4*)&s_wih[j*20];
      const float4* w1r = (const float4*)&s_wih[(16+j)*20];
      const float4* w2r = (const float4*)&s_wih[(32+j)*20];
      #pragma unroll
      for (int q4 = 0; q4 < 5; ++q4) {
        float4 w0 = w0r[q4], w1 = w1r[q4], w2 = w2r[q4];
        float a0 = xv[q4*4+0], a1 = xv[q4*4+1], a2 = xv[q4*4+2], a3 = xv[q4*4+3];
        g0 = fmaf(a0,w0.x,g0); g0 = fmaf(a1,w0.y,g0); g0 = fmaf(a2,w0.z,g0); g0 = fmaf(a3,w0.w,g0);
        g1 = fmaf(a0,w1.x,g1); g1 = fmaf(a1,w1.y,g1); g1 = fmaf(a2,w1.z,g1); g1 = fmaf(a3,w1.w,g1);
        g2 = fmaf(a0,w2.x,g2); g2 = fmaf(a1,w2.y,g2); g2 = fmaf(a2,w2.z,g2); g2 = fmaf(a3,w2.w,g2);
      }
      float t0 = s_bhh[j], t1 = s_bhh[16+j], t2 = s_bhh[32+j];
      const float4* h0r = (const float4*)&s_whh[j*16];
      const float4* h1r = (const float4*)&s_whh[(16+j)*16];
      const float4* h2r = (const float4*)&s_whh[(32+j)*16];
      #pragma unroll
      for (int q4 = 0; q4 < 4; ++q4) {
        float4 w0 = h0r[q4], w1 = h1r[q4], w2 = h2r[q4];
        float a0 = h[q4*4+0], a1 = h[q4*4+1], a2 = h[q4*4+2], a3 = h[q4*4+3];
        t0 = fmaf(a0,w0.x,t0); t0 = fmaf(a1,w0.y,t0); t0 = fmaf(a2,w0.z,t0); t0 = fmaf(a3,w0.w,t0);
        t1 = fmaf(a0,w1.x,t1); t1 = fmaf(a1,w1.y,t1); t1 = fmaf(a2,w1.z,t1); t1 = fmaf(a3,w1.w,t1);
        t2 = fmaf(a0,w2.x,t2); t2 = fmaf(a1,w2.y,t2); t2 = fmaf(a2,w2.z,t2); t2 = fmaf(a3,w2.w,t2);
      }
      float r = sigm_f(g0 + t0);
      float z = sigm_f(g1 + t1);
      float nn = tanhf(fmaf(r, t2, g2));
      hn[jj] = fmaf(z, h[j], (1.0f - z)*nn);
    }
    // exchange hn -> full h
    *(float4*)&s_h[li*16 + ch0] = *(float4*)hn;
    #pragma unroll
    for (int g = 0; g < 4; ++g) {
      float4 t = *(const float4*)&s_h[li*16 + g*4];
      h[g*4]=t.x; h[g*4+1]=t.y; h[g*4+2]=t.z; h[g*4+3]=t.w;
    }

    #pragma unroll
    for (int d = 0; d < 8; ++d) {
      const float4* wr = (const float4*)&s_offw[d*16];
      float s = s_offb[d];
      #pragma unroll
      for (int q4 = 0; q4 < 4; ++q4) {
        float4 w4 = wr[q4];
        s = fmaf(h[q4*4+0], w4.x, s); s = fmaf(h[q4*4+1], w4.y, s);
        s = fmaf(h[q4*4+2], w4.z, s); s = fmaf(h[q4*4+3], w4.w, s);
      }
      off_[d] += s;
    }
    #pragma unroll
    for (int p = 0; p < 4; ++p) {
      const float4* wr = (const float4*)&s_aw[p*16];
      float s = s_ab[p];
      #pragma unroll
      for (int q4 = 0; q4 < 4; ++q4) {
        float4 w4 = wr[q4];
        s = fmaf(h[q4*4+0], w4.x, s); s = fmaf(h[q4*4+1], w4.y, s);
        s = fmaf(h[q4*4+2], w4.z, s); s = fmaf(h[q4*4+3], w4.w, s);
      }
      attn_[p] += s;
    }
  }

  // ---- softmax over (N,P) + entropy (all lanes redundantly; identical results) ----
  float lg[16];
  #pragma unroll
  for (int n = 0; n < 4; ++n) {
    float tv = tbb[(b*8+head)*4 + n];
    #pragma unroll
    for (int p = 0; p < 4; ++p) lg[n*4+p] = attn_[p] + tv;
  }
  float mx = lg[0];
  #pragma unroll
  for (int i = 1; i < 16; ++i) mx = fmaxf(mx, lg[i]);
  float es = 0.f;
  #pragma unroll
  for (int i = 0; i < 16; ++i){ lg[i] = expf(lg[i]-mx); es += lg[i]; }
  float inv = 1.0f/es;
  float ent = 0.f;
  #pragma unroll
  for (int i = 0; i < 16; ++i){ lg[i] *= inv; ent -= lg[i]*logf(lg[i] + 1e-8f); }
  if (lq == 0) entb[item] = ent;

  // ---- deformable sampling: lane handles p=lq (4 n-images, n-inner order preserved) ----
  float acc[16];
  #pragma unroll
  for (int j = 0; j < 16; ++j) acc[j] = 0.f;
  {
    Bilin bl = make_bilin(x, y, off_[2*lq], off_[2*lq+1]);
    #pragma unroll
    for (int n = 0; n < 4; ++n) {
      const float* vpn = vs + (size_t)((b*4+n)*8 + head)*kM;
      float smp[16];
      sample16(vpn, bl, smp);
      float wnp = lg[n*4+lq];
      #pragma unroll
      for (int j = 0; j < 16; ++j) acc[j] = fmaf(wnp, smp[j], acc[j]);
    }
  }
  // cross-p pairwise reduce within quad
  #pragma unroll
  for (int j = 0; j < 16; ++j) acc[j] += __shfl_xor(acc[j], 1);
  #pragma unroll
  for (int j = 0; j < 16; ++j) acc[j] += __shfl_xor(acc[j], 2);
  // lane stores its channel quarter
  float4 t = {acc[ch0+0],acc[ch0+1],acc[ch0+2],acc[ch0+3]};
  *(float4*)(outattn + (size_t)item*16 + ch0) = t;
}

// ---------------- entropy mean over heads -> confidence/entropy outputs (f32) ----------------
__global__ __launch_bounds__(256) void ent_k(const float* __restrict__ entb, float* __restrict__ outf)
{
  int idx = blockIdx.x*256 + threadIdx.x;   // B*HW = 18432
  int b = idx / kHW, yx = idx % kHW;
  float s = 0.f;
  #pragma unroll
  for (int h8 = 0; h8 < 8; ++h8) s += entb[(b*8+h8)*kHW + yx];
  s *= 0.125f;
  float conf = 1.0f - fminf(fmaxf(s / (2.772588722239781f + 1e-8f), 0.0f), 1.0f);
  outf[2359296 + idx]         = conf;
  outf[2359296 + 18432 + idx] = s;
}

extern "C" void kernel_launch(void* const* d_in, const int* in_sizes, int n_in,
                              void* d_out, int out_size, void* d_ws, size_t ws_size,
                              hipStream_t stream)
{
  const float* query  = (const float*)d_in[0];
  const float* values = (const float*)d_in[1];
  const float* relt   = (const float*)d_in[2];
  const float* time_enc = (const float*)d_in[3];
  const float* qw  = (const float*)d_in[4];
  const float* qb  = (const float*)d_in[5];
  const float* vw  = (const float*)d_in[6];
  const float* vb  = (const float*)d_in[7];
  const float* dww = (const float*)d_in[8];
  const float* dwb = (const float*)d_in[9];
  const float* pww = (const float*)d_in[10];
  const float* pwb = (const float*)d_in[11];
  const float* wih = (const float*)d_in[12];
  const float* whh = (const float*)d_in[13];
  const float* bih = (const float*)d_in[14];
  const float* bhh = (const float*)d_in[15];
  const float* offw = (const float*)d_in[16];
  const float* offb = (const float*)d_in[17];
  const float* aw  = (const float*)d_in[18];
  const float* ab  = (const float*)d_in[19];
  const float* tw  = (const float*)d_in[20];
  const float* tb  = (const float*)d_in[21];
  const float* o1w = (const float*)d_in[22];
  const float* o1b = (const float*)d_in[23];
  const float* o2w = (const float*)d_in[24];
  const float* o2b = (const float*)d_in[25];
  const float* gate = (const float*)d_in[26];
  float* out = (float*)d_out;
  float* ws = (float*)d_ws;

  // workspace layout (f32 elements)
  float* vsb    = ws;                 // v item-major [(b,n,head)][yx][16] : 9437184
  float* qbuf   = ws +  9437184;      // q item-major [(b,head)][yx][16]   : 2359296 ; reused as o1 mid (planar)
  float* netb   = ws + 11796480;      // net item-major [bh][yx][16]       : 2359296
  float* dwbuf  = ws + 14155776;      // depthwise out planar [b][c][yx]   : 2359296 ; reused as outattn item-major
  float* entbf  = ws + 18284544;      // per-head entropy [item]           :  147456
  float* tbbuf  = ws + 18432000;      // time bias (B,H,N)                 :      64
  float* wtbuf  = ws + 18432064;      // 5 transposed weights              :   81920
  if (ws_size < 18513984ull * 4ull) return;   // ~74.1 MB required

  float* wt_q  = wtbuf;
  float* wt_v  = wtbuf + 16384;
  float* wt_pw = wtbuf + 32768;
  float* wt_o1 = wtbuf + 49152;
  float* wt_o2 = wtbuf + 65536;

  dim3 blk(256,1,1);
  // 0. transpose weights
  prep_k<<<dim3(64,5,1), blk, 0, stream>>>(qw, vw, pww, o1w, o2w, wtbuf);
  // 1. q = conv1x1(query) -> item-major qbuf
  gemm1x1_k<0,0><<<dim3(72,2,1), blk, 0, stream>>>(query, wt_q, qb, qbuf, nullptr);
  // 2. v = conv1x1(values) -> item-major vsb
  gemm1x1_k<0,0><<<dim3(72,8,1), blk, 0, stream>>>(values, wt_v, vb, vsb, nullptr);
  // 3. depthwise 7x7 + gelu -> planar dwbuf
  dw_k<<<dim3(9216,1,1), blk, 0, stream>>>(query, dww, dwb, dwbuf);
  // 4. pointwise -> initial GRU state, item-major netb; consumes dwbuf
  gemm1x1_k<0,0><<<dim3(72,2,1), blk, 0, stream>>>(dwbuf, wt_pw, pwb, netb, nullptr);
  // 5. time bias
  tb_k<<<dim3(1,1,1), dim3(64,1,1), 0, stream>>>(time_enc, tw, tb, tbbuf);
  // 6. FUSED v2 (4 lanes/item): corr + 3x GRU + softmax/sampling/entropy -> dwbuf
  fused_k<<<dim3(2304,1,1), blk, 0, stream>>>(qbuf, vsb, netb, relt,
                                              wih, whh, bih, bhh, offw, offb, aw, ab,
                                              tbbuf, dwbuf, entbf);
  // 7. entropy mean / confidence -> d_out tail (f32)
  ent_k<<<dim3(72,1,1), blk, 0, stream>>>(entbf, out);
  // 8. o1 + gelu: item-major dwbuf -> planar qbuf (mid)
  gemm1x1_k<1,1><<<dim3(72,2,1), blk, 0, stream>>>(dwbuf, wt_o1, o1b, qbuf, nullptr);
  // 9. o2 * sigmoid(gate): planar qbuf -> f32 d_out
  gemm1x1_k<0,2><<<dim3(72,2,1), blk, 0, stream>>>(qbuf, wt_o2, o2b, out, gate);
}

// Round 7
// 1097.865 us; speedup vs baseline: 1.2538x; 1.2538x over previous
//
#include <hip/hip_runtime.h>
#include <hip/hip_bf16.h>

typedef unsigned short u16;
typedef unsigned int   u32;

// Problem constants: B=2, N=4, C=128, HEADS=8, P=4, H=W=96, TC=64, ITERS=3, HD=16
constexpr int kHW = 9216;       // 96*96
constexpr int kM  = 147456;     // 16*9216 (item-major image stride; also B*HEADS*HW items)

__device__ __forceinline__ float gelu_f(float v){ return 0.5f*v*(1.0f+erff(v*0.70710678118654752f)); }
__device__ __forceinline__ float sigm_f(float v){ return 1.0f/(1.0f+expf(-v)); }
__device__ __forceinline__ float bf2f(u16 u){ return __uint_as_float(((u32)u)<<16); }
__device__ __forceinline__ u16 f2bf(float f){
  u32 x = __float_as_uint(f);
  return (u16)((x + 0x7fffu + ((x>>16)&1u)) >> 16);   // RNE
}
__device__ __forceinline__ int nearest_n(const float* __restrict__ relt, int b){
  int nidx = 0; float bv = fabsf(relt[b*4]);
  for (int n = 1; n < 4; ++n){ float a = fabsf(relt[b*4+n]); if (a < bv){ bv=a; nidx=n; } }
  return nidx;
}

struct Bilin { int i00,i10,i01,i11; float w00,w10,w01,w11; };

__device__ __forceinline__ Bilin make_bilin(int x, int y, float ox, float oy){
  float gx = fmaf((float)x, 2.0f/95.0f, -1.0f);
  float gy = fmaf((float)y, 2.0f/95.0f, -1.0f);
  float sgx = fminf(fmaxf(gx+ox,-1.0f),1.0f);
  float sgy = fminf(fmaxf(gy+oy,-1.0f),1.0f);
  float ix = (sgx+1.0f)*0.5f*95.0f;
  float iy = (sgy+1.0f)*0.5f*95.0f;
  float x0f = floorf(ix), y0f = floorf(iy);
  float wx = ix-x0f, wy = iy-y0f;
  int x0 = min(max((int)x0f,0),95), y0 = min(max((int)y0f,0),95);
  int x1 = min(x0+1,95), y1 = min(y0+1,95);
  Bilin b;
  b.i00=(y0*96+x0)*16; b.i10=(y0*96+x1)*16; b.i01=(y1*96+x0)*16; b.i11=(y1*96+x1)*16;
  float iwx=1.0f-wx, iwy=1.0f-wy;
  b.w00=iwx*iwy; b.w10=wx*iwy; b.w01=iwx*wy; b.w11=wx*wy;
  return b;
}

__device__ __forceinline__ void sample16(const float* __restrict__ vp, const Bilin& bl, float* __restrict__ o){
  const float4* p00 = (const float4*)(vp + bl.i00);
  const float4* p10 = (const float4*)(vp + bl.i10);
  const float4* p01 = (const float4*)(vp + bl.i01);
  const float4* p11 = (const float4*)(vp + bl.i11);
  #pragma unroll
  for (int g = 0; g < 4; ++g){
    float4 a=p00[g], b=p10[g], c=p01[g], d=p11[g];
    o[g*4+0] = a.x*bl.w00 + b.x*bl.w10 + c.x*bl.w01 + d.x*bl.w11;
    o[g*4+1] = a.y*bl.w00 + b.y*bl.w10 + c.y*bl.w01 + d.y*bl.w11;
    o[g*4+2] = a.z*bl.w00 + b.z*bl.w10 + c.z*bl.w01 + d.z*bl.w11;
    o[g*4+3] = a.w*bl.w00 + b.w*bl.w10 + c.w*bl.w01 + d.w*bl.w11;
  }
}

// bf16 variant: same per-channel FMA order, inputs rounded to bf16
__device__ __forceinline__ void sample16_bf(const u16* __restrict__ vp, const Bilin& bl, float* __restrict__ o){
  uint4 a0 = *(const uint4*)(vp + bl.i00), a1 = *(const uint4*)(vp + bl.i00 + 8);
  uint4 b0 = *(const uint4*)(vp + bl.i10), b1 = *(const uint4*)(vp + bl.i10 + 8);
  uint4 c0 = *(const uint4*)(vp + bl.i01), c1 = *(const uint4*)(vp + bl.i01 + 8);
  uint4 d0 = *(const uint4*)(vp + bl.i11), d1 = *(const uint4*)(vp + bl.i11 + 8);
  u32 aw[8] = {a0.x,a0.y,a0.z,a0.w,a1.x,a1.y,a1.z,a1.w};
  u32 bw[8] = {b0.x,b0.y,b0.z,b0.w,b1.x,b1.y,b1.z,b1.w};
  u32 cw[8] = {c0.x,c0.y,c0.z,c0.w,c1.x,c1.y,c1.z,c1.w};
  u32 dw[8] = {d0.x,d0.y,d0.z,d0.w,d1.x,d1.y,d1.z,d1.w};
  #pragma unroll
  for (int g = 0; g < 8; ++g){
    float alo = __uint_as_float(aw[g]<<16), ahi = __uint_as_float(aw[g]&0xffff0000u);
    float blo = __uint_as_float(bw[g]<<16), bhi = __uint_as_float(bw[g]&0xffff0000u);
    float clo = __uint_as_float(cw[g]<<16), chi = __uint_as_float(cw[g]&0xffff0000u);
    float dlo = __uint_as_float(dw[g]<<16), dhi = __uint_as_float(dw[g]&0xffff0000u);
    o[g*2+0] = alo*bl.w00 + blo*bl.w10 + clo*bl.w01 + dlo*bl.w11;
    o[g*2+1] = ahi*bl.w00 + bhi*bl.w10 + chi*bl.w01 + dhi*bl.w11;
  }
}

// ---------------- transpose the five (C,C) weight matrices into [c][o] f32 ----------------
__global__ __launch_bounds__(256) void prep_k(const float* __restrict__ qw, const float* __restrict__ vw,
    const float* __restrict__ pww, const float* __restrict__ o1w, const float* __restrict__ o2w,
    float* __restrict__ wt)
{
  const float* src = (blockIdx.y==0)?qw:(blockIdx.y==1)?vw:(blockIdx.y==2)?pww:(blockIdx.y==3)?o1w:o2w;
  float* d = wt + blockIdx.y*16384;
  int i = blockIdx.x*256 + threadIdx.x;
  int o = i & 127, c = i >> 7;
  d[i] = src[o*128 + c];
}

// ---------------- conv1x1 as register-tiled GEMM ----------------
// ASRC: 0 = planar f32 [c][px], 2 = item-major bf16 [bh][px][16]
// EPI : 0 = item-major f32 [bh][px][16], 1 = gelu planar f32, 2 = gate planar f32,
//       3 = v-epilogue: bf16 item-major always + f32 item-major if n==nearest(b)
template<int ASRC, int EPI>
__global__ __launch_bounds__(256, 3) void gemm1x1_k(const void* __restrict__ inp,
    const float* __restrict__ wt, const float* __restrict__ bias,
    float* __restrict__ outf, u16* __restrict__ out16,
    const float* __restrict__ gate, const float* __restrict__ relt)
{
  __shared__ __align__(16) float a_s[16*132];
  __shared__ __align__(16) float b_s[16*132];
  const int tid = threadIdx.x;
  const int tx = tid & 15, ty = tid >> 4;
  const int img = blockIdx.y;
  const int px0 = blockIdx.x * 128;
  const int sr = tid >> 4;
  const int sc = (tid & 15) * 8;

  float acc[64];
  #pragma unroll
  for (int oj = 0; oj < 8; ++oj) {
    float bv = bias[tx*8+oj];
    #pragma unroll
    for (int pi = 0; pi < 8; ++pi) acc[pi*8+oj] = bv;
  }

  for (int kc = 0; kc < 8; ++kc) {
    const int k0 = kc*16;
    { const float4* g = (const float4*)(wt + (k0+sr)*128 + sc);
      float4 v0 = g[0], v1 = g[1];
      *(float4*)&b_s[sr*132+sc] = v0; *(float4*)&b_s[sr*132+sc+4] = v1; }
    if (ASRC == 0) {
      const float* inf = (const float*)inp;
      const float4* g = (const float4*)(inf + (size_t)(img*128 + k0 + sr)*kHW + px0 + sc);
      float4 v0 = g[0], v1 = g[1];
      *(float4*)&a_s[sr*132+sc] = v0; *(float4*)&a_s[sr*132+sc+4] = v1;
    } else {
      const u16* g16 = (const u16*)inp;
      const int px = tid >> 1, hd0 = (tid & 1)*8;
      uint4 raw = *(const uint4*)(g16 + ((size_t)(img*8 + kc)*kHW + px0 + px)*16 + hd0);
      u32 w[4] = {raw.x, raw.y, raw.z, raw.w};
      #pragma unroll
      for (int gi = 0; gi < 4; ++gi) {
        a_s[(hd0+gi*2+0)*132+px] = __uint_as_float(w[gi]<<16);
        a_s[(hd0+gi*2+1)*132+px] = __uint_as_float(w[gi]&0xffff0000u);
      }
    }
    __syncthreads();
    #pragma unroll
    for (int k = 0; k < 16; ++k) {
      float4 b0 = *(const float4*)&b_s[k*132 + tx*8];
      float4 b1 = *(const float4*)&b_s[k*132 + tx*8 + 4];
      float4 a0 = *(const float4*)&a_s[k*132 + ty*8];
      float4 a1 = *(const float4*)&a_s[k*132 + ty*8 + 4];
      float av[8] = {a0.x,a0.y,a0.z,a0.w,a1.x,a1.y,a1.z,a1.w};
      float bv[8] = {b0.x,b0.y,b0.z,b0.w,b1.x,b1.y,b1.z,b1.w};
      #pragma unroll
      for (int pi = 0; pi < 8; ++pi)
        #pragma unroll
        for (int oj = 0; oj < 8; ++oj)
          acc[pi*8+oj] = fmaf(av[pi], bv[oj], acc[pi*8+oj]);
    }
    __syncthreads();
  }

  if (EPI == 0) {
    const int head = tx >> 1, hd0 = (tx & 1)*8;
    #pragma unroll
    for (int pi = 0; pi < 8; ++pi) {
      const int px = px0 + ty*8 + pi;
      float* dst = outf + ((size_t)(img*8 + head)*kHW + px)*16 + hd0;
      float4 t0 = {acc[pi*8+0],acc[pi*8+1],acc[pi*8+2],acc[pi*8+3]};
      float4 t1 = {acc[pi*8+4],acc[pi*8+5],acc[pi*8+6],acc[pi*8+7]};
      *(float4*)dst = t0; *(float4*)(dst+4) = t1;
    }
  } else if (EPI == 3) {
    const int b = img >> 2, n = img & 3;
    const int nidx = nearest_n(relt, b);
    const int head = tx >> 1, hd0 = (tx & 1)*8;
    #pragma unroll
    for (int pi = 0; pi < 8; ++pi) {
      const int px = px0 + ty*8 + pi;
      // bf16 copy (all n)
      u16* d16 = out16 + ((size_t)(img*8 + head)*kHW + px)*16 + hd0;
      uint4 packed;
      packed.x = (u32)f2bf(acc[pi*8+0]) | ((u32)f2bf(acc[pi*8+1])<<16);
      packed.y = (u32)f2bf(acc[pi*8+2]) | ((u32)f2bf(acc[pi*8+3])<<16);
      packed.z = (u32)f2bf(acc[pi*8+4]) | ((u32)f2bf(acc[pi*8+5])<<16);
      packed.w = (u32)f2bf(acc[pi*8+6]) | ((u32)f2bf(acc[pi*8+7])<<16);
      *(uint4*)d16 = packed;
      if (n == nidx) {           // f32 copy of nearest image (for corr + GRU sampling)
        float* dst = outf + ((size_t)(b*8 + head)*kHW + px)*16 + hd0;
        float4 t0 = {acc[pi*8+0],acc[pi*8+1],acc[pi*8+2],acc[pi*8+3]};
        float4 t1 = {acc[pi*8+4],acc[pi*8+5],acc[pi*8+6],acc[pi*8+7]};
        *(float4*)dst = t0; *(float4*)(dst+4) = t1;
      }
    }
  } else {
    #pragma unroll
    for (int oj = 0; oj < 8; ++oj) {
      const int o = tx*8 + oj;
      float* dst = outf + (size_t)(img*128 + o)*kHW + px0 + ty*8;
      float v[8];
      #pragma unroll
      for (int pi = 0; pi < 8; ++pi) {
        float t = acc[pi*8+oj];
        v[pi] = (EPI == 1) ? gelu_f(t) : t * sigm_f(gate[o]);
      }
      float4 t0 = {v[0],v[1],v[2],v[3]};
      float4 t1 = {v[4],v[5],v[6],v[7]};
      *(float4*)dst = t0; *(float4*)(dst+4) = t1;
    }
  }
}

// ---------------- depthwise 7x7 + bias + exact gelu ----------------
__global__ __launch_bounds__(256) void dw_k(const float* __restrict__ q, const float* __restrict__ dww,
    const float* __restrict__ dwb, float* __restrict__ outf)
{
  int idx = blockIdx.x*256 + threadIdx.x;
  int px = idx % kHW;
  int bc = idx / kHW;
  int c = bc & 127;
  int x = px % 96, y = px / 96;
  float s = dwb[c];
  const float* qb = q + (size_t)bc*kHW;
  #pragma unroll
  for (int ky = 0; ky < 7; ++ky) {
    int yy = y + ky - 3;
    if (yy < 0 || yy > 95) continue;
    #pragma unroll
    for (int kx = 0; kx < 7; ++kx) {
      int xx = x + kx - 3;
      if (xx < 0 || xx > 95) continue;
      s = fmaf(qb[yy*96+xx], dww[c*49 + ky*7 + kx], s);
    }
  }
  outf[idx] = gelu_f(s);
}

// ---------------- time bias: (B,HEADS,N) ----------------
__global__ void tb_k(const float* __restrict__ te, const float* __restrict__ tw,
                     const float* __restrict__ tbias, float* __restrict__ tbb)
{
  int i = threadIdx.x;
  if (i >= 64) return;
  int b = i >> 5, h = (i >> 2) & 7, n = i & 3;
  float s = tbias[h];
  for (int tc = 0; tc < 64; ++tc) s = fmaf(te[(b*4+n)*64 + tc], tw[h*64+tc], s);
  tbb[(b*8+h)*4 + n] = s;
}

// ---------------- FUSED v3: 2 lanes/item, corr+GRU duplicated, final sampling n-split ----
// r5 locality preserved (wave = 32 consecutive pixels; duplicate loads broadcast).
__global__ __launch_bounds__(256, 3) void fused_k(
    const float* __restrict__ qb, const float* __restrict__ vf32, const u16* __restrict__ vb16,
    const float* __restrict__ netb, const float* __restrict__ relt,
    const float* __restrict__ wih, const float* __restrict__ whh,
    const float* __restrict__ bihp, const float* __restrict__ bhhp,
    const float* __restrict__ offw, const float* __restrict__ offbp,
    const float* __restrict__ aw, const float* __restrict__ abp,
    const float* __restrict__ tbb,
    u16* __restrict__ outattn16, float* __restrict__ entb)
{
  __shared__ __align__(16) float s_wih[48*20];   // rows padded 18->20 (pad=0)
  __shared__ __align__(16) float s_whh[48*16];
  __shared__ __align__(16) float s_offw[8*16];
  __shared__ __align__(16) float s_aw[4*16];
  __shared__ float s_bih[48], s_bhh[48], s_offb[8], s_ab[4];
  const int tid = threadIdx.x;
  for (int i = tid; i < 960; i += 256){ int g = i/20, k = i%20; s_wih[i] = (k<18)? wih[g*18+k] : 0.0f; }
  for (int i = tid; i < 768; i += 256) s_whh[i] = whh[i];
  if (tid < 128) s_offw[tid] = offw[tid];
  if (tid < 64)  s_aw[tid]  = aw[tid];
  if (tid < 48){ s_bih[tid] = bihp[tid]; s_bhh[tid] = bhhp[tid]; }
  if (tid < 8)   s_offb[tid] = offbp[tid];
  if (tid < 4)   s_ab[tid]  = abp[tid];

  const int li = tid >> 1;           // item-in-block 0..127
  const int lq = tid & 1;            // lane-in-pair
  // XCD swizzle: 1152 blocks = 8 XCDs x 144; XCD x covers bh {2x, 2x+1} (~4.7 MB v in L2)
  const int vblk = (blockIdx.x & 7)*144 + (blockIdx.x >> 3);
  const int item = vblk*128 + li;
  const int yx = item % kHW; const int bh = item / kHW;
  const int b = bh >> 3, head = bh & 7;
  const int x = yx % 96, y = yx / 96;
  const int nidx = nearest_n(relt, b);
  const float* vp = vf32 + (size_t)(b*8 + head)*kM;   // nearest-n image, f32

  // ---- correlation argmax (f64, duplicated in both lanes -> identical) ----
  float off_[8], attn_[4];
  {
    float qv[16];
    { const float4* q4 = (const float4*)(qb + (size_t)bh*kM + yx*16);
      #pragma unroll
      for (int g = 0; g < 4; ++g){ float4 t = q4[g]; qv[g*4]=t.x; qv[g*4+1]=t.y; qv[g*4+2]=t.z; qv[g*4+3]=t.w; } }
    const int sdx[5] = {0,-1,1,0,0};   // SHIFTS entries are (dx,dy)
    const int sdy[5] = {0,0,0,-1,1};
    double bsc = 0.0; int best = 0;
    #pragma unroll
    for (int s5 = 0; s5 < 5; ++s5) {
      int sy = y - sdy[s5], sx = x - sdx[s5];
      double sc = 0.0;
      if (sy >= 0 && sy < 96 && sx >= 0 && sx < 96) {
        const float* tp = vp + (sy*96+sx)*16;
        #pragma unroll
        for (int hd = 0; hd < 16; ++hd) sc += (double)qv[hd]*(double)tp[hd];
      }
      if (s5 == 0) { bsc = sc; best = 0; }
      else if (sc > bsc) { bsc = sc; best = s5; }
    }
    const float STEP = 2.0f/96.0f;
    float ox = 0.f, oy = 0.f;        // reference swap: x-offset = dy*2/W, y-offset = dx*2/H
    if (best == 3) ox = -STEP; else if (best == 4) ox = STEP;
    if (best == 1) oy = -STEP; else if (best == 2) oy = STEP;
    #pragma unroll
    for (int p = 0; p < 4; ++p) { off_[2*p] = ox; off_[2*p+1] = oy; attn_[p] = 0.0f; }
  }

  float h[16];
  { const float4* n4 = (const float4*)(netb + (size_t)item*16);
    #pragma unroll
    for (int g = 0; g < 4; ++g){ float4 t = n4[g]; h[g*4]=t.x; h[g*4+1]=t.y; h[g*4+2]=t.z; h[g*4+3]=t.w; } }

  __syncthreads();   // LDS weights ready

  // ---- 3 GRU refinement iterations (duplicated in both lanes, f32 sampling) ----
  for (int it = 0; it < 3; ++it) {
    const float p0x = off_[0];
    const float p0y = off_[1];
    Bilin bl = make_bilin(x, y, p0x, p0y);
    float xv[20];
    sample16(vp, bl, xv);
    xv[16] = p0x; xv[17] = p0y; xv[18] = 0.f; xv[19] = 0.f;

    float hn[16];
    #pragma unroll 2
    for (int j = 0; j < 16; ++j) {
      float g0 = s_bih[j], g1 = s_bih[16+j], g2 = s_bih[32+j];
      const float4* w0r = (const float4*)&s_wih[j*20];
      const float4* w1r = (const float4*)&s_wih[(16+j)*20];
      const float4* w2r = (const float4*)&s_wih[(32+j)*20];
      #pragma unroll
      for (int q4 = 0; q4 < 5; ++q4) {
        float4 w0 = w0r[q4], w1 = w1r[q4], w2 = w2r[q4];
        float a0 = xv[q4*4+0], a1 = xv[q4*4+1], a2 = xv[q4*4+2], a3 = xv[q4*4+3];
        g0 = fmaf(a0,w0.x,g0); g0 = fmaf(a1,w0.y,g0); g0 = fmaf(a2,w0.z,g0); g0 = fmaf(a3,w0.w,g0);
        g1 = fmaf(a0,w1.x,g1); g1 = fmaf(a1,w1.y,g1); g1 = fmaf(a2,w1.z,g1); g1 = fmaf(a3,w1.w,g1);
        g2 = fmaf(a0,w2.x,g2); g2 = fmaf(a1,w2.y,g2); g2 = fmaf(a2,w2.z,g2); g2 = fmaf(a3,w2.w,g2);
      }
      float t0 = s_bhh[j], t1 = s_bhh[16+j], t2 = s_bhh[32+j];
      const float4* h0r = (const float4*)&s_whh[j*16];
      const float4* h1r = (const float4*)&s_whh[(16+j)*16];
      const float4* h2r = (const float4*)&s_whh[(32+j)*16];
      #pragma unroll
      for (int q4 = 0; q4 < 4; ++q4) {
        float4 w0 = h0r[q4], w1 = h1r[q4], w2 = h2r[q4];
        float a0 = h[q4*4+0], a1 = h[q4*4+1], a2 = h[q4*4+2], a3 = h[q4*4+3];
        t0 = fmaf(a0,w0.x,t0); t0 = fmaf(a1,w0.y,t0); t0 = fmaf(a2,w0.z,t0); t0 = fmaf(a3,w0.w,t0);
        t1 = fmaf(a0,w1.x,t1); t1 = fmaf(a1,w1.y,t1); t1 = fmaf(a2,w1.z,t1); t1 = fmaf(a3,w1.w,t1);
        t2 = fmaf(a0,w2.x,t2); t2 = fmaf(a1,w2.y,t2); t2 = fmaf(a2,w2.z,t2); t2 = fmaf(a3,w2.w,t2);
      }
      float r = sigm_f(g0 + t0);
      float z = sigm_f(g1 + t1);
      float nn = tanhf(fmaf(r, t2, g2));
      hn[j] = fmaf(z, h[j], (1.0f - z)*nn);
    }
    #pragma unroll
    for (int j = 0; j < 16; ++j) h[j] = hn[j];

    #pragma unroll
    for (int d = 0; d < 8; ++d) {
      const float4* wr = (const float4*)&s_offw[d*16];
      float s = s_offb[d];
      #pragma unroll
      for (int q4 = 0; q4 < 4; ++q4) {
        float4 w4 = wr[q4];
        s = fmaf(h[q4*4+0], w4.x, s); s = fmaf(h[q4*4+1], w4.y, s);
        s = fmaf(h[q4*4+2], w4.z, s); s = fmaf(h[q4*4+3], w4.w, s);
      }
      off_[d] += s;
    }
    #pragma unroll
    for (int p = 0; p < 4; ++p) {
      const float4* wr = (const float4*)&s_aw[p*16];
      float s = s_ab[p];
      #pragma unroll
      for (int q4 = 0; q4 < 4; ++q4) {
        float4 w4 = wr[q4];
        s = fmaf(h[q4*4+0], w4.x, s); s = fmaf(h[q4*4+1], w4.y, s);
        s = fmaf(h[q4*4+2], w4.z, s); s = fmaf(h[q4*4+3], w4.w, s);
      }
      attn_[p] += s;
    }
  }

  // ---- softmax over (N,P) + entropy (duplicated; identical) ----
  float lg[16];
  #pragma unroll
  for (int n = 0; n < 4; ++n) {
    float tv = tbb[(b*8+head)*4 + n];
    #pragma unroll
    for (int p = 0; p < 4; ++p) lg[n*4+p] = attn_[p] + tv;
  }
  float mx = lg[0];
  #pragma unroll
  for (int i = 1; i < 16; ++i) mx = fmaxf(mx, lg[i]);
  float es = 0.f;
  #pragma unroll
  for (int i = 0; i < 16; ++i){ lg[i] = expf(lg[i]-mx); es += lg[i]; }
  float inv = 1.0f/es;
  float ent = 0.f;
  #pragma unroll
  for (int i = 0; i < 16; ++i){ lg[i] *= inv; ent -= lg[i]*logf(lg[i] + 1e-8f); }
  if (lq == 0) entb[item] = ent;

  // ---- deformable sampling (bf16 v): p-outer preserved, n split 2/2 across pair ----
  float acc[16];
  #pragma unroll
  for (int j = 0; j < 16; ++j) acc[j] = 0.f;
  #pragma unroll
  for (int p = 0; p < 4; ++p) {
    Bilin bl = make_bilin(x, y, off_[2*p], off_[2*p+1]);
    #pragma unroll
    for (int nn = 0; nn < 2; ++nn) {
      const int n = lq*2 + nn;
      const u16* vpn = vb16 + (size_t)((b*4+n)*8 + head)*kM;
      float smp[16];
      sample16_bf(vpn, bl, smp);
      float wnp = lg[n*4+p];
      #pragma unroll
      for (int j = 0; j < 16; ++j) acc[j] = fmaf(wnp, smp[j], acc[j]);
    }
  }
  #pragma unroll
  for (int j = 0; j < 16; ++j) acc[j] += __shfl_xor(acc[j], 1);
  // lane stores its bf16 half (32B per item total)
  const int c0 = lq*8;
  uint4 packed;
  packed.x = (u32)f2bf(acc[c0+0]) | ((u32)f2bf(acc[c0+1])<<16);
  packed.y = (u32)f2bf(acc[c0+2]) | ((u32)f2bf(acc[c0+3])<<16);
  packed.z = (u32)f2bf(acc[c0+4]) | ((u32)f2bf(acc[c0+5])<<16);
  packed.w = (u32)f2bf(acc[c0+6]) | ((u32)f2bf(acc[c0+7])<<16);
  *(uint4*)(outattn16 + (size_t)item*16 + c0) = packed;
}

// ---------------- entropy mean over heads -> confidence/entropy outputs (f32) ----------------
__global__ __launch_bounds__(256) void ent_k(const float* __restrict__ entb, float* __restrict__ outf)
{
  int idx = blockIdx.x*256 + threadIdx.x;   // B*HW = 18432
  int b = idx / kHW, yx = idx % kHW;
  float s = 0.f;
  #pragma unroll
  for (int h8 = 0; h8 < 8; ++h8) s += entb[(b*8+h8)*kHW + yx];
  s *= 0.125f;
  float conf = 1.0f - fminf(fmaxf(s / (2.772588722239781f + 1e-8f), 0.0f), 1.0f);
  outf[2359296 + idx]         = conf;
  outf[2359296 + 18432 + idx] = s;
}

extern "C" void kernel_launch(void* const* d_in, const int* in_sizes, int n_in,
                              void* d_out, int out_size, void* d_ws, size_t ws_size,
                              hipStream_t stream)
{
  const float* query  = (const float*)d_in[0];
  const float* values = (const float*)d_in[1];
  const float* relt   = (const float*)d_in[2];
  const float* time_enc = (const float*)d_in[3];
  const float* qw  = (const float*)d_in[4];
  const float* qb  = (const float*)d_in[5];
  const float* vw  = (const float*)d_in[6];
  const float* vb  = (const float*)d_in[7];
  const float* dww = (const float*)d_in[8];
  const float* dwb = (const float*)d_in[9];
  const float* pww = (const float*)d_in[10];
  const float* pwb = (const float*)d_in[11];
  const float* wih = (const float*)d_in[12];
  const float* whh = (const float*)d_in[13];
  const float* bih = (const float*)d_in[14];
  const float* bhh = (const float*)d_in[15];
  const float* offw = (const float*)d_in[16];
  const float* offb = (const float*)d_in[17];
  const float* aw  = (const float*)d_in[18];
  const float* ab  = (const float*)d_in[19];
  const float* tw  = (const float*)d_in[20];
  const float* tb  = (const float*)d_in[21];
  const float* o1w = (const float*)d_in[22];
  const float* o1b = (const float*)d_in[23];
  const float* o2w = (const float*)d_in[24];
  const float* o2b = (const float*)d_in[25];
  const float* gate = (const float*)d_in[26];
  float* out = (float*)d_out;
  float* ws = (float*)d_ws;

  // workspace layout (f32 slots) — total 14385280 slots = 57.5 MB
  u16*   vb16   = (u16*)ws;                        // bf16 v, item-major [(b,n,h)][yx][16] : 4718592 fl
  float* vf32n  = ws + 4718592;                    // f32 v of nearest n [(b,h)][yx][16]   : 2359296
  float* qbuf   = ws + 7077888;                    // q item-major [(b,h)][yx][16]          : 2359296 ; reused as o1 mid (planar)
  float* netb   = ws + 9437184;                    // net item-major [bh][yx][16]           : 2359296
  float* dwbuf  = ws + 11796480;                   // dw mid planar [b][c][yx]              : 2359296 ; first half reused as outattn16
  u16*   oat16  = (u16*)dwbuf;                     // outattn bf16 [item][16]               : 2359296 u16
  float* entbf  = ws + 14155776;                   // per-head entropy                      :  147456
  float* tbbuf  = ws + 14303232;                   // time bias                             :      64
  float* wtbuf  = ws + 14303360;                   // 5 transposed weights                  :   81920
  if (ws_size < 14385280ull * 4ull) return;

  float* wt_q  = wtbuf;
  float* wt_v  = wtbuf + 16384;
  float* wt_pw = wtbuf + 32768;
  float* wt_o1 = wtbuf + 49152;
  float* wt_o2 = wtbuf + 65536;

  dim3 blk(256,1,1);
  // 0. transpose weights
  prep_k<<<dim3(64,5,1), blk, 0, stream>>>(qw, vw, pww, o1w, o2w, wtbuf);
  // 1. q = conv1x1(query) -> item-major f32 qbuf
  gemm1x1_k<0,0><<<dim3(72,2,1), blk, 0, stream>>>(query, wt_q, qb, qbuf, nullptr, nullptr, nullptr);
  // 2. depthwise 7x7 + gelu -> planar dwbuf
  dw_k<<<dim3(9216,1,1), blk, 0, stream>>>(query, dww, dwb, dwbuf);
  // 3. pointwise -> initial GRU state item-major netb (consumes dwbuf)
  gemm1x1_k<0,0><<<dim3(72,2,1), blk, 0, stream>>>(dwbuf, wt_pw, pwb, netb, nullptr, nullptr, nullptr);
  // 4. v = conv1x1(values) -> bf16 all + f32 nearest (after dwbuf consumers; vb16 region separate)
  gemm1x1_k<0,3><<<dim3(72,8,1), blk, 0, stream>>>(values, wt_v, vb, vf32n, vb16, nullptr, relt);
  // 5. time bias
  tb_k<<<dim3(1,1,1), dim3(64,1,1), 0, stream>>>(time_enc, tw, tb, tbbuf);
  // 6. FUSED v3 (2 lanes/item): corr + 3x GRU + softmax/sampling/entropy -> oat16 (in dwbuf)
  fused_k<<<dim3(1152,1,1), blk, 0, stream>>>(qbuf, vf32n, vb16, netb, relt,
                                              wih, whh, bih, bhh, offw, offb, aw, ab,
                                              tbbuf, oat16, entbf);
  // 7. entropy mean / confidence -> d_out tail (f32)
  ent_k<<<dim3(72,1,1), blk, 0, stream>>>(entbf, out);
  // 8. o1 + gelu: bf16 item-major oat16 -> planar f32 qbuf (mid)
  gemm1x1_k<2,1><<<dim3(72,2,1), blk, 0, stream>>>(oat16, wt_o1, o1b, qbuf, nullptr, nullptr, nullptr);
  // 9. o2 * sigmoid(gate): planar qbuf -> f32 d_out
  gemm1x1_k<0,2><<<dim3(72,2,1), blk, 0, stream>>>(qbuf, wt_o2, o2b, out, nullptr, gate, nullptr);
}

// Round 8
// 756.020 us; speedup vs baseline: 1.8207x; 1.4522x over previous
//
#include <hip/hip_runtime.h>
#include <hip/hip_bf16.h>

typedef unsigned short u16;
typedef unsigned int   u32;

// Problem constants: B=2, N=4, C=128, HEADS=8, P=4, H=W=96, TC=64, ITERS=3, HD=16
constexpr int kHW = 9216;       // 96*96
constexpr int kM  = 147456;     // 16*9216 (item-major image stride; also B*HEADS*HW items)

__device__ __forceinline__ float gelu_f(float v){ return 0.5f*v*(1.0f+erff(v*0.70710678118654752f)); }
__device__ __forceinline__ float sigm_f(float v){ return 1.0f/(1.0f+expf(-v)); }
__device__ __forceinline__ u16 f2bf(float f){
  u32 x = __float_as_uint(f);
  return (u16)((x + 0x7fffu + ((x>>16)&1u)) >> 16);   // RNE
}
__device__ __forceinline__ int nearest_n(const float* __restrict__ relt, int b){
  int nidx = 0; float bv = fabsf(relt[b*4]);
  for (int n = 1; n < 4; ++n){ float a = fabsf(relt[b*4+n]); if (a < bv){ bv=a; nidx=n; } }
  return nidx;
}

struct Bilin { int i00,i10,i01,i11; float w00,w10,w01,w11; };

__device__ __forceinline__ Bilin make_bilin(int x, int y, float ox, float oy){
  float gx = fmaf((float)x, 2.0f/95.0f, -1.0f);
  float gy = fmaf((float)y, 2.0f/95.0f, -1.0f);
  float sgx = fminf(fmaxf(gx+ox,-1.0f),1.0f);
  float sgy = fminf(fmaxf(gy+oy,-1.0f),1.0f);
  float ix = (sgx+1.0f)*0.5f*95.0f;
  float iy = (sgy+1.0f)*0.5f*95.0f;
  float x0f = floorf(ix), y0f = floorf(iy);
  float wx = ix-x0f, wy = iy-y0f;
  int x0 = min(max((int)x0f,0),95), y0 = min(max((int)y0f,0),95);
  int x1 = min(x0+1,95), y1 = min(y0+1,95);
  Bilin b;
  b.i00=(y0*96+x0)*16; b.i10=(y0*96+x1)*16; b.i01=(y1*96+x0)*16; b.i11=(y1*96+x1)*16;
  float iwx=1.0f-wx, iwy=1.0f-wy;
  b.w00=iwx*iwy; b.w10=wx*iwy; b.w01=iwx*wy; b.w11=wx*wy;
  return b;
}

__device__ __forceinline__ void sample16(const float* __restrict__ vp, const Bilin& bl, float* __restrict__ o){
  const float4* p00 = (const float4*)(vp + bl.i00);
  const float4* p10 = (const float4*)(vp + bl.i10);
  const float4* p01 = (const float4*)(vp + bl.i01);
  const float4* p11 = (const float4*)(vp + bl.i11);
  #pragma unroll
  for (int g = 0; g < 4; ++g){
    float4 a=p00[g], b=p10[g], c=p01[g], d=p11[g];
    o[g*4+0] = a.x*bl.w00 + b.x*bl.w10 + c.x*bl.w01 + d.x*bl.w11;
    o[g*4+1] = a.y*bl.w00 + b.y*bl.w10 + c.y*bl.w01 + d.y*bl.w11;
    o[g*4+2] = a.z*bl.w00 + b.z*bl.w10 + c.z*bl.w01 + d.z*bl.w11;
    o[g*4+3] = a.w*bl.w00 + b.w*bl.w10 + c.w*bl.w01 + d.w*bl.w11;
  }
}

// bf16 variant: same per-channel FMA order, inputs rounded to bf16
__device__ __forceinline__ void sample16_bf(const u16* __restrict__ vp, const Bilin& bl, float* __restrict__ o){
  uint4 a0 = *(const uint4*)(vp + bl.i00), a1 = *(const uint4*)(vp + bl.i00 + 8);
  uint4 b0 = *(const uint4*)(vp + bl.i10), b1 = *(const uint4*)(vp + bl.i10 + 8);
  uint4 c0 = *(const uint4*)(vp + bl.i01), c1 = *(const uint4*)(vp + bl.i01 + 8);
  uint4 d0 = *(const uint4*)(vp + bl.i11), d1 = *(const uint4*)(vp + bl.i11 + 8);
  u32 aw[8] = {a0.x,a0.y,a0.z,a0.w,a1.x,a1.y,a1.z,a1.w};
  u32 bw[8] = {b0.x,b0.y,b0.z,b0.w,b1.x,b1.y,b1.z,b1.w};
  u32 cw[8] = {c0.x,c0.y,c0.z,c0.w,c1.x,c1.y,c1.z,c1.w};
  u32 dw[8] = {d0.x,d0.y,d0.z,d0.w,d1.x,d1.y,d1.z,d1.w};
  #pragma unroll
  for (int g = 0; g < 8; ++g){
    float alo = __uint_as_float(aw[g]<<16), ahi = __uint_as_float(aw[g]&0xffff0000u);
    float blo = __uint_as_float(bw[g]<<16), bhi = __uint_as_float(bw[g]&0xffff0000u);
    float clo = __uint_as_float(cw[g]<<16), chi = __uint_as_float(cw[g]&0xffff0000u);
    float dlo = __uint_as_float(dw[g]<<16), dhi = __uint_as_float(dw[g]&0xffff0000u);
    o[g*2+0] = alo*bl.w00 + blo*bl.w10 + clo*bl.w01 + dlo*bl.w11;
    o[g*2+1] = ahi*bl.w00 + bhi*bl.w10 + chi*bl.w01 + dhi*bl.w11;
  }
}

// ---------------- transpose the five (C,C) weight matrices into [c][o] f32 ----------------
__global__ __launch_bounds__(256) void prep_k(const float* __restrict__ qw, const float* __restrict__ vw,
    const float* __restrict__ pww, const float* __restrict__ o1w, const float* __restrict__ o2w,
    float* __restrict__ wt)
{
  const float* src = (blockIdx.y==0)?qw:(blockIdx.y==1)?vw:(blockIdx.y==2)?pww:(blockIdx.y==3)?o1w:o2w;
  float* d = wt + blockIdx.y*16384;
  int i = blockIdx.x*256 + threadIdx.x;
  int o = i & 127, c = i >> 7;
  d[i] = src[o*128 + c];
}

// ---------------- conv1x1 as register-tiled GEMM ----------------
// ASRC: 0 = planar f32 [c][px], 2 = item-major bf16 [bh][px][16]
// EPI : 0 = item-major f32 [bh][px][16], 1 = gelu planar f32, 2 = gate planar f32,
//       3 = v-epilogue: bf16 item-major always + f32 item-major if n==nearest(b)
template<int ASRC, int EPI>
__global__ __launch_bounds__(256, 3) void gemm1x1_k(const void* __restrict__ inp,
    const float* __restrict__ wt, const float* __restrict__ bias,
    float* __restrict__ outf, u16* __restrict__ out16,
    const float* __restrict__ gate, const float* __restrict__ relt)
{
  __shared__ __align__(16) float a_s[16*132];
  __shared__ __align__(16) float b_s[16*132];
  const int tid = threadIdx.x;
  const int tx = tid & 15, ty = tid >> 4;
  const int img = blockIdx.y;
  const int px0 = blockIdx.x * 128;
  const int sr = tid >> 4;
  const int sc = (tid & 15) * 8;

  float acc[64];
  #pragma unroll
  for (int oj = 0; oj < 8; ++oj) {
    float bv = bias[tx*8+oj];
    #pragma unroll
    for (int pi = 0; pi < 8; ++pi) acc[pi*8+oj] = bv;
  }

  for (int kc = 0; kc < 8; ++kc) {
    const int k0 = kc*16;
    { const float4* g = (const float4*)(wt + (k0+sr)*128 + sc);
      float4 v0 = g[0], v1 = g[1];
      *(float4*)&b_s[sr*132+sc] = v0; *(float4*)&b_s[sr*132+sc+4] = v1; }
    if (ASRC == 0) {
      const float* inf = (const float*)inp;
      const float4* g = (const float4*)(inf + (size_t)(img*128 + k0 + sr)*kHW + px0 + sc);
      float4 v0 = g[0], v1 = g[1];
      *(float4*)&a_s[sr*132+sc] = v0; *(float4*)&a_s[sr*132+sc+4] = v1;
    } else {
      const u16* g16 = (const u16*)inp;
      const int px = tid >> 1, hd0 = (tid & 1)*8;
      uint4 raw = *(const uint4*)(g16 + ((size_t)(img*8 + kc)*kHW + px0 + px)*16 + hd0);
      u32 w[4] = {raw.x, raw.y, raw.z, raw.w};
      #pragma unroll
      for (int gi = 0; gi < 4; ++gi) {
        a_s[(hd0+gi*2+0)*132+px] = __uint_as_float(w[gi]<<16);
        a_s[(hd0+gi*2+1)*132+px] = __uint_as_float(w[gi]&0xffff0000u);
      }
    }
    __syncthreads();
    #pragma unroll
    for (int k = 0; k < 16; ++k) {
      float4 b0 = *(const float4*)&b_s[k*132 + tx*8];
      float4 b1 = *(const float4*)&b_s[k*132 + tx*8 + 4];
      float4 a0 = *(const float4*)&a_s[k*132 + ty*8];
      float4 a1 = *(const float4*)&a_s[k*132 + ty*8 + 4];
      float av[8] = {a0.x,a0.y,a0.z,a0.w,a1.x,a1.y,a1.z,a1.w};
      float bv[8] = {b0.x,b0.y,b0.z,b0.w,b1.x,b1.y,b1.z,b1.w};
      #pragma unroll
      for (int pi = 0; pi < 8; ++pi)
        #pragma unroll
        for (int oj = 0; oj < 8; ++oj)
          acc[pi*8+oj] = fmaf(av[pi], bv[oj], acc[pi*8+oj]);
    }
    __syncthreads();
  }

  if (EPI == 0) {
    const int head = tx >> 1, hd0 = (tx & 1)*8;
    #pragma unroll
    for (int pi = 0; pi < 8; ++pi) {
      const int px = px0 + ty*8 + pi;
      float* dst = outf + ((size_t)(img*8 + head)*kHW + px)*16 + hd0;
      float4 t0 = {acc[pi*8+0],acc[pi*8+1],acc[pi*8+2],acc[pi*8+3]};
      float4 t1 = {acc[pi*8+4],acc[pi*8+5],acc[pi*8+6],acc[pi*8+7]};
      *(float4*)dst = t0; *(float4*)(dst+4) = t1;
    }
  } else if (EPI == 3) {
    const int b = img >> 2, n = img & 3;
    const int nidx = nearest_n(relt, b);
    const int head = tx >> 1, hd0 = (tx & 1)*8;
    #pragma unroll
    for (int pi = 0; pi < 8; ++pi) {
      const int px = px0 + ty*8 + pi;
      u16* d16 = out16 + ((size_t)(img*8 + head)*kHW + px)*16 + hd0;
      uint4 packed;
      packed.x = (u32)f2bf(acc[pi*8+0]) | ((u32)f2bf(acc[pi*8+1])<<16);
      packed.y = (u32)f2bf(acc[pi*8+2]) | ((u32)f2bf(acc[pi*8+3])<<16);
      packed.z = (u32)f2bf(acc[pi*8+4]) | ((u32)f2bf(acc[pi*8+5])<<16);
      packed.w = (u32)f2bf(acc[pi*8+6]) | ((u32)f2bf(acc[pi*8+7])<<16);
      *(uint4*)d16 = packed;
      if (n == nidx) {           // f32 copy of nearest image (for corr + GRU sampling)
        float* dst = outf + ((size_t)(b*8 + head)*kHW + px)*16 + hd0;
        float4 t0 = {acc[pi*8+0],acc[pi*8+1],acc[pi*8+2],acc[pi*8+3]};
        float4 t1 = {acc[pi*8+4],acc[pi*8+5],acc[pi*8+6],acc[pi*8+7]};
        *(float4*)dst = t0; *(float4*)(dst+4) = t1;
      }
    }
  } else {
    #pragma unroll
    for (int oj = 0; oj < 8; ++oj) {
      const int o = tx*8 + oj;
      float* dst = outf + (size_t)(img*128 + o)*kHW + px0 + ty*8;
      float v[8];
      #pragma unroll
      for (int pi = 0; pi < 8; ++pi) {
        float t = acc[pi*8+oj];
        v[pi] = (EPI == 1) ? gelu_f(t) : t * sigm_f(gate[o]);
      }
      float4 t0 = {v[0],v[1],v[2],v[3]};
      float4 t1 = {v[4],v[5],v[6],v[7]};
      *(float4*)dst = t0; *(float4*)(dst+4) = t1;
    }
  }
}

// ---------------- depthwise 7x7 + bias + exact gelu ----------------
__global__ __launch_bounds__(256) void dw_k(const float* __restrict__ q, const float* __restrict__ dww,
    const float* __restrict__ dwb, float* __restrict__ outf)
{
  int idx = blockIdx.x*256 + threadIdx.x;
  int px = idx % kHW;
  int bc = idx / kHW;
  int c = bc & 127;
  int x = px % 96, y = px / 96;
  float s = dwb[c];
  const float* qb = q + (size_t)bc*kHW;
  #pragma unroll
  for (int ky = 0; ky < 7; ++ky) {
    int yy = y + ky - 3;
    if (yy < 0 || yy > 95) continue;
    #pragma unroll
    for (int kx = 0; kx < 7; ++kx) {
      int xx = x + kx - 3;
      if (xx < 0 || xx > 95) continue;
      s = fmaf(qb[yy*96+xx], dww[c*49 + ky*7 + kx], s);
    }
  }
  outf[idx] = gelu_f(s);
}

// ---------------- time bias: (B,HEADS,N) ----------------
__global__ void tb_k(const float* __restrict__ te, const float* __restrict__ tw,
                     const float* __restrict__ tbias, float* __restrict__ tbb)
{
  int i = threadIdx.x;
  if (i >= 64) return;
  int b = i >> 5, h = (i >> 2) & 7, n = i & 3;
  float s = tbias[h];
  for (int tc = 0; tc < 64; ++tc) s = fmaf(te[(b*4+n)*64 + tc], tw[h*64+tc], s);
  tbb[(b*8+h)*4 + n] = s;
}

// ---------------- FUSED v4: r5 structure (1 lane/item) + bf16 final sampling ----------------
__global__ __launch_bounds__(256, 3) void fused_k(
    const float* __restrict__ qb, const float* __restrict__ vf32, const u16* __restrict__ vb16,
    const float* __restrict__ netb, const float* __restrict__ relt,
    const float* __restrict__ wih, const float* __restrict__ whh,
    const float* __restrict__ bihp, const float* __restrict__ bhhp,
    const float* __restrict__ offw, const float* __restrict__ offbp,
    const float* __restrict__ aw, const float* __restrict__ abp,
    const float* __restrict__ tbb,
    u16* __restrict__ outattn16, float* __restrict__ entb)
{
  __shared__ __align__(16) float s_wih[48*20];   // rows padded 18->20 (pad=0)
  __shared__ __align__(16) float s_whh[48*16];
  __shared__ __align__(16) float s_offw[8*16];
  __shared__ __align__(16) float s_aw[4*16];
  __shared__ float s_bih[48], s_bhh[48], s_offb[8], s_ab[4];
  const int tid = threadIdx.x;
  for (int i = tid; i < 960; i += 256){ int g = i/20, k = i%20; s_wih[i] = (k<18)? wih[g*18+k] : 0.0f; }
  for (int i = tid; i < 768; i += 256) s_whh[i] = whh[i];
  if (tid < 128) s_offw[tid] = offw[tid];
  if (tid < 64)  s_aw[tid]  = aw[tid];
  if (tid < 48){ s_bih[tid] = bihp[tid]; s_bhh[tid] = bhhp[tid]; }
  if (tid < 8)   s_offb[tid] = offbp[tid];
  if (tid < 4)   s_ab[tid]  = abp[tid];

  // XCD swizzle (r5-validated): 576 blocks = 8 XCDs x 72
  const int vblk = (blockIdx.x & 7)*72 + (blockIdx.x >> 3);
  const int item = vblk*256 + tid;
  const int yx = item % kHW; const int bh = item / kHW;
  const int b = bh >> 3, head = bh & 7;
  const int x = yx % 96, y = yx / 96;
  const float* vp = vf32 + (size_t)(b*8 + head)*kM;   // nearest-n image, f32

  // ---- correlation argmax (f64 accumulation, matches numpy ordering) ----
  float off_[8], attn_[4];
  {
    float qv[16];
    { const float4* q4 = (const float4*)(qb + (size_t)bh*kM + yx*16);
      #pragma unroll
      for (int g = 0; g < 4; ++g){ float4 t = q4[g]; qv[g*4]=t.x; qv[g*4+1]=t.y; qv[g*4+2]=t.z; qv[g*4+3]=t.w; } }
    const int sdx[5] = {0,-1,1,0,0};   // SHIFTS entries are (dx,dy)
    const int sdy[5] = {0,0,0,-1,1};
    double bsc = 0.0; int best = 0;
    #pragma unroll
    for (int s5 = 0; s5 < 5; ++s5) {
      int sy = y - sdy[s5], sx = x - sdx[s5];
      double sc = 0.0;
      if (sy >= 0 && sy < 96 && sx >= 0 && sx < 96) {
        const float* tp = vp + (sy*96+sx)*16;
        #pragma unroll
        for (int hd = 0; hd < 16; ++hd) sc += (double)qv[hd]*(double)tp[hd];
      }
      if (s5 == 0) { bsc = sc; best = 0; }
      else if (sc > bsc) { bsc = sc; best = s5; }
    }
    const float STEP = 2.0f/96.0f;
    float ox = 0.f, oy = 0.f;        // reference swap: x-offset = dy*2/W, y-offset = dx*2/H
    if (best == 3) ox = -STEP; else if (best == 4) ox = STEP;
    if (best == 1) oy = -STEP; else if (best == 2) oy = STEP;
    #pragma unroll
    for (int p = 0; p < 4; ++p) { off_[2*p] = ox; off_[2*p+1] = oy; attn_[p] = 0.0f; }
  }

  float h[16];
  { const float4* n4 = (const float4*)(netb + (size_t)item*16);
    #pragma unroll
    for (int g = 0; g < 4; ++g){ float4 t = n4[g]; h[g*4]=t.x; h[g*4+1]=t.y; h[g*4+2]=t.z; h[g*4+3]=t.w; } }

  __syncthreads();   // LDS weights ready

  // ---- 3 GRU refinement iterations, all state in registers (f32 sampling) ----
  for (int it = 0; it < 3; ++it) {
    const float p0x = off_[0];
    const float p0y = off_[1];
    Bilin bl = make_bilin(x, y, p0x, p0y);
    float xv[20];
    sample16(vp, bl, xv);
    xv[16] = p0x; xv[17] = p0y; xv[18] = 0.f; xv[19] = 0.f;

    float hn[16];
    #pragma unroll 2
    for (int j = 0; j < 16; ++j) {
      float g0 = s_bih[j], g1 = s_bih[16+j], g2 = s_bih[32+j];
      const float4* w0r = (const float4*)&s_wih[j*20];
      const float4* w1r = (const float4*)&s_wih[(16+j)*20];
      const float4* w2r = (const float4*)&s_wih[(32+j)*20];
      #pragma unroll
      for (int q4 = 0; q4 < 5; ++q4) {
        float4 w0 = w0r[q4], w1 = w1r[q4], w2 = w2r[q4];
        float a0 = xv[q4*4+0], a1 = xv[q4*4+1], a2 = xv[q4*4+2], a3 = xv[q4*4+3];
        g0 = fmaf(a0,w0.x,g0); g0 = fmaf(a1,w0.y,g0); g0 = fmaf(a2,w0.z,g0); g0 = fmaf(a3,w0.w,g0);
        g1 = fmaf(a0,w1.x,g1); g1 = fmaf(a1,w1.y,g1); g1 = fmaf(a2,w1.z,g1); g1 = fmaf(a3,w1.w,g1);
        g2 = fmaf(a0,w2.x,g2); g2 = fmaf(a1,w2.y,g2); g2 = fmaf(a2,w2.z,g2); g2 = fmaf(a3,w2.w,g2);
      }
      float t0 = s_bhh[j], t1 = s_bhh[16+j], t2 = s_bhh[32+j];
      const float4* h0r = (const float4*)&s_whh[j*16];
      const float4* h1r = (const float4*)&s_whh[(16+j)*16];
      const float4* h2r = (const float4*)&s_whh[(32+j)*16];
      #pragma unroll
      for (int q4 = 0; q4 < 4; ++q4) {
        float4 w0 = h0r[q4], w1 = h1r[q4], w2 = h2r[q4];
        float a0 = h[q4*4+0], a1 = h[q4*4+1], a2 = h[q4*4+2], a3 = h[q4*4+3];
        t0 = fmaf(a0,w0.x,t0); t0 = fmaf(a1,w0.y,t0); t0 = fmaf(a2,w0.z,t0); t0 = fmaf(a3,w0.w,t0);
        t1 = fmaf(a0,w1.x,t1); t1 = fmaf(a1,w1.y,t1); t1 = fmaf(a2,w1.z,t1); t1 = fmaf(a3,w1.w,t1);
        t2 = fmaf(a0,w2.x,t2); t2 = fmaf(a1,w2.y,t2); t2 = fmaf(a2,w2.z,t2); t2 = fmaf(a3,w2.w,t2);
      }
      float r = sigm_f(g0 + t0);
      float z = sigm_f(g1 + t1);
      float nn = tanhf(fmaf(r, t2, g2));
      hn[j] = fmaf(z, h[j], (1.0f - z)*nn);
    }
    #pragma unroll
    for (int j = 0; j < 16; ++j) h[j] = hn[j];

    #pragma unroll
    for (int d = 0; d < 8; ++d) {
      const float4* wr = (const float4*)&s_offw[d*16];
      float s = s_offb[d];
      #pragma unroll
      for (int q4 = 0; q4 < 4; ++q4) {
        float4 w4 = wr[q4];
        s = fmaf(h[q4*4+0], w4.x, s); s = fmaf(h[q4*4+1], w4.y, s);
        s = fmaf(h[q4*4+2], w4.z, s); s = fmaf(h[q4*4+3], w4.w, s);
      }
      off_[d] += s;
    }
    #pragma unroll
    for (int p = 0; p < 4; ++p) {
      const float4* wr = (const float4*)&s_aw[p*16];
      float s = s_ab[p];
      #pragma unroll
      for (int q4 = 0; q4 < 4; ++q4) {
        float4 w4 = wr[q4];
        s = fmaf(h[q4*4+0], w4.x, s); s = fmaf(h[q4*4+1], w4.y, s);
        s = fmaf(h[q4*4+2], w4.z, s); s = fmaf(h[q4*4+3], w4.w, s);
      }
      attn_[p] += s;
    }
  }

  // ---- softmax over (N,P) + entropy ----
  float lg[16];
  #pragma unroll
  for (int n = 0; n < 4; ++n) {
    float tv = tbb[(b*8+head)*4 + n];
    #pragma unroll
    for (int p = 0; p < 4; ++p) lg[n*4+p] = attn_[p] + tv;
  }
  float mx = lg[0];
  #pragma unroll
  for (int i = 1; i < 16; ++i) mx = fmaxf(mx, lg[i]);
  float es = 0.f;
  #pragma unroll
  for (int i = 0; i < 16; ++i){ lg[i] = expf(lg[i]-mx); es += lg[i]; }
  float inv = 1.0f/es;
  float ent = 0.f;
  #pragma unroll
  for (int i = 0; i < 16; ++i){ lg[i] *= inv; ent -= lg[i]*logf(lg[i] + 1e-8f); }
  entb[item] = ent;

  // ---- N*P deformable sampling (bf16 v), p-outer n-inner (r5 order) ----
  float acc[16];
  #pragma unroll
  for (int j = 0; j < 16; ++j) acc[j] = 0.f;
  #pragma unroll
  for (int p = 0; p < 4; ++p) {
    Bilin bl = make_bilin(x, y, off_[2*p], off_[2*p+1]);
    #pragma unroll
    for (int n = 0; n < 4; ++n) {
      const u16* vpn = vb16 + (size_t)((b*4+n)*8 + head)*kM;
      float smp[16];
      sample16_bf(vpn, bl, smp);
      float wnp = lg[n*4+p];
      #pragma unroll
      for (int j = 0; j < 16; ++j) acc[j] = fmaf(wnp, smp[j], acc[j]);
    }
  }
  // bf16 item-major store (32 B contiguous per item)
  uint4 pk0, pk1;
  pk0.x = (u32)f2bf(acc[0])  | ((u32)f2bf(acc[1])<<16);
  pk0.y = (u32)f2bf(acc[2])  | ((u32)f2bf(acc[3])<<16);
  pk0.z = (u32)f2bf(acc[4])  | ((u32)f2bf(acc[5])<<16);
  pk0.w = (u32)f2bf(acc[6])  | ((u32)f2bf(acc[7])<<16);
  pk1.x = (u32)f2bf(acc[8])  | ((u32)f2bf(acc[9])<<16);
  pk1.y = (u32)f2bf(acc[10]) | ((u32)f2bf(acc[11])<<16);
  pk1.z = (u32)f2bf(acc[12]) | ((u32)f2bf(acc[13])<<16);
  pk1.w = (u32)f2bf(acc[14]) | ((u32)f2bf(acc[15])<<16);
  *(uint4*)(outattn16 + (size_t)item*16)     = pk0;
  *(uint4*)(outattn16 + (size_t)item*16 + 8) = pk1;
}

// ---------------- entropy mean over heads -> confidence/entropy outputs (f32) ----------------
__global__ __launch_bounds__(256) void ent_k(const float* __restrict__ entb, float* __restrict__ outf)
{
  int idx = blockIdx.x*256 + threadIdx.x;   // B*HW = 18432
  int b = idx / kHW, yx = idx % kHW;
  float s = 0.f;
  #pragma unroll
  for (int h8 = 0; h8 < 8; ++h8) s += entb[(b*8+h8)*kHW + yx];
  s *= 0.125f;
  float conf = 1.0f - fminf(fmaxf(s / (2.772588722239781f + 1e-8f), 0.0f), 1.0f);
  outf[2359296 + idx]         = conf;
  outf[2359296 + 18432 + idx] = s;
}

extern "C" void kernel_launch(void* const* d_in, const int* in_sizes, int n_in,
                              void* d_out, int out_size, void* d_ws, size_t ws_size,
                              hipStream_t stream)
{
  const float* query  = (const float*)d_in[0];
  const float* values = (const float*)d_in[1];
  const float* relt   = (const float*)d_in[2];
  const float* time_enc = (const float*)d_in[3];
  const float* qw  = (const float*)d_in[4];
  const float* qb  = (const float*)d_in[5];
  const float* vw  = (const float*)d_in[6];
  const float* vb  = (const float*)d_in[7];
  const float* dww = (const float*)d_in[8];
  const float* dwb = (const float*)d_in[9];
  const float* pww = (const float*)d_in[10];
  const float* pwb = (const float*)d_in[11];
  const float* wih = (const float*)d_in[12];
  const float* whh = (const float*)d_in[13];
  const float* bih = (const float*)d_in[14];
  const float* bhh = (const float*)d_in[15];
  const float* offw = (const float*)d_in[16];
  const float* offb = (const float*)d_in[17];
  const float* aw  = (const float*)d_in[18];
  const float* ab  = (const float*)d_in[19];
  const float* tw  = (const float*)d_in[20];
  const float* tb  = (const float*)d_in[21];
  const float* o1w = (const float*)d_in[22];
  const float* o1b = (const float*)d_in[23];
  const float* o2w = (const float*)d_in[24];
  const float* o2b = (const float*)d_in[25];
  const float* gate = (const float*)d_in[26];
  float* out = (float*)d_out;
  float* ws = (float*)d_ws;

  // workspace layout (f32 slots) — total 14385280 slots = 57.5 MB
  u16*   vb16   = (u16*)ws;                        // bf16 v, item-major [(b,n,h)][yx][16] : 4718592 fl
  float* vf32n  = ws + 4718592;                    // f32 v of nearest n [(b,h)][yx][16]   : 2359296
  float* qbuf   = ws + 7077888;                    // q item-major [(b,h)][yx][16]          : 2359296 ; reused as o1 mid (planar)
  float* netb   = ws + 9437184;                    // net item-major [bh][yx][16]           : 2359296
  float* dwbuf  = ws + 11796480;                   // dw mid planar [b][c][yx]              : 2359296 ; first half reused as outattn16
  u16*   oat16  = (u16*)dwbuf;                     // outattn bf16 [item][16]               : 2359296 u16
  float* entbf  = ws + 14155776;                   // per-head entropy                      :  147456
  float* tbbuf  = ws + 14303232;                   // time bias                             :      64
  float* wtbuf  = ws + 14303360;                   // 5 transposed weights                  :   81920
  if (ws_size < 14385280ull * 4ull) return;

  float* wt_q  = wtbuf;
  float* wt_v  = wtbuf + 16384;
  float* wt_pw = wtbuf + 32768;
  float* wt_o1 = wtbuf + 49152;
  float* wt_o2 = wtbuf + 65536;

  dim3 blk(256,1,1);
  // 0. transpose weights
  prep_k<<<dim3(64,5,1), blk, 0, stream>>>(qw, vw, pww, o1w, o2w, wtbuf);
  // 1. q = conv1x1(query) -> item-major f32 qbuf
  gemm1x1_k<0,0><<<dim3(72,2,1), blk, 0, stream>>>(query, wt_q, qb, qbuf, nullptr, nullptr, nullptr);
  // 2. depthwise 7x7 + gelu -> planar dwbuf
  dw_k<<<dim3(9216,1,1), blk, 0, stream>>>(query, dww, dwb, dwbuf);
  // 3. pointwise -> initial GRU state item-major netb (consumes dwbuf)
  gemm1x1_k<0,0><<<dim3(72,2,1), blk, 0, stream>>>(dwbuf, wt_pw, pwb, netb, nullptr, nullptr, nullptr);
  // 4. v = conv1x1(values) -> bf16 all + f32 nearest
  gemm1x1_k<0,3><<<dim3(72,8,1), blk, 0, stream>>>(values, wt_v, vb, vf32n, vb16, nullptr, relt);
  // 5. time bias
  tb_k<<<dim3(1,1,1), dim3(64,1,1), 0, stream>>>(time_enc, tw, tb, tbbuf);
  // 6. FUSED v4 (1 lane/item, bf16 final sampling) -> oat16 (in dwbuf)
  fused_k<<<dim3(576,1,1), blk, 0, stream>>>(qbuf, vf32n, vb16, netb, relt,
                                             wih, whh, bih, bhh, offw, offb, aw, ab,
                                             tbbuf, oat16, entbf);
  // 7. entropy mean / confidence -> d_out tail (f32)
  ent_k<<<dim3(72,1,1), blk, 0, stream>>>(entbf, out);
  // 8. o1 + gelu: bf16 item-major oat16 -> planar f32 qbuf (mid)
  gemm1x1_k<2,1><<<dim3(72,2,1), blk, 0, stream>>>(oat16, wt_o1, o1b, qbuf, nullptr, nullptr, nullptr);
  // 9. o2 * sigmoid(gate): planar qbuf -> f32 d_out
  gemm1x1_k<0,2><<<dim3(72,2,1), blk, 0, stream>>>(qbuf, wt_o2, o2b, out, nullptr, gate, nullptr);
}

// Round 9
// 469.850 us; speedup vs baseline: 2.9296x; 1.6091x over previous
//
#include <hip/hip_runtime.h>
#include <hip/hip_bf16.h>

typedef unsigned short u16;
typedef unsigned int   u32;

// Problem constants: B=2, N=4, C=128, HEADS=8, P=4, H=W=96, TC=64, ITERS=3, HD=16
constexpr int kHW = 9216;       // 96*96
constexpr int kM  = 147456;     // 16*9216 (item-major image stride; also B*HEADS*HW items)

__device__ __forceinline__ float gelu_f(float v){ return 0.5f*v*(1.0f+erff(v*0.70710678118654752f)); }
__device__ __forceinline__ float sigm_f(float v){ return 1.0f/(1.0f+expf(-v)); }
__device__ __forceinline__ u16 f2bf(float f){
  u32 x = __float_as_uint(f);
  return (u16)((x + 0x7fffu + ((x>>16)&1u)) >> 16);   // RNE
}
__device__ __forceinline__ int nearest_n(const float* __restrict__ relt, int b){
  int nidx = 0; float bv = fabsf(relt[b*4]);
  for (int n = 1; n < 4; ++n){ float a = fabsf(relt[b*4+n]); if (a < bv){ bv=a; nidx=n; } }
  return nidx;
}

struct Bilin { int i00,i10,i01,i11; float w00,w10,w01,w11; };

__device__ __forceinline__ Bilin make_bilin(int x, int y, float ox, float oy){
  float gx = fmaf((float)x, 2.0f/95.0f, -1.0f);
  float gy = fmaf((float)y, 2.0f/95.0f, -1.0f);
  float sgx = fminf(fmaxf(gx+ox,-1.0f),1.0f);
  float sgy = fminf(fmaxf(gy+oy,-1.0f),1.0f);
  float ix = (sgx+1.0f)*0.5f*95.0f;
  float iy = (sgy+1.0f)*0.5f*95.0f;
  float x0f = floorf(ix), y0f = floorf(iy);
  float wx = ix-x0f, wy = iy-y0f;
  int x0 = min(max((int)x0f,0),95), y0 = min(max((int)y0f,0),95);
  int x1 = min(x0+1,95), y1 = min(y0+1,95);
  Bilin b;
  b.i00=(y0*96+x0)*16; b.i10=(y0*96+x1)*16; b.i01=(y1*96+x0)*16; b.i11=(y1*96+x1)*16;
  float iwx=1.0f-wx, iwy=1.0f-wy;
  b.w00=iwx*iwy; b.w10=wx*iwy; b.w01=iwx*wy; b.w11=wx*wy;
  return b;
}

__device__ __forceinline__ void sample16(const float* __restrict__ vp, const Bilin& bl, float* __restrict__ o){
  const float4* p00 = (const float4*)(vp + bl.i00);
  const float4* p10 = (const float4*)(vp + bl.i10);
  const float4* p01 = (const float4*)(vp + bl.i01);
  const float4* p11 = (const float4*)(vp + bl.i11);
  #pragma unroll
  for (int g = 0; g < 4; ++g){
    float4 a=p00[g], b=p10[g], c=p01[g], d=p11[g];
    o[g*4+0] = a.x*bl.w00 + b.x*bl.w10 + c.x*bl.w01 + d.x*bl.w11;
    o[g*4+1] = a.y*bl.w00 + b.y*bl.w10 + c.y*bl.w01 + d.y*bl.w11;
    o[g*4+2] = a.z*bl.w00 + b.z*bl.w10 + c.z*bl.w01 + d.z*bl.w11;
    o[g*4+3] = a.w*bl.w00 + b.w*bl.w10 + c.w*bl.w01 + d.w*bl.w11;
  }
}

// ---------------- transpose the five (C,C) weight matrices into [c][o] f32 ----------------
__global__ __launch_bounds__(256) void prep_k(const float* __restrict__ qw, const float* __restrict__ vw,
    const float* __restrict__ pww, const float* __restrict__ o1w, const float* __restrict__ o2w,
    float* __restrict__ wt)
{
  const float* src = (blockIdx.y==0)?qw:(blockIdx.y==1)?vw:(blockIdx.y==2)?pww:(blockIdx.y==3)?o1w:o2w;
  float* d = wt + blockIdx.y*16384;
  int i = blockIdx.x*256 + threadIdx.x;
  int o = i & 127, c = i >> 7;
  d[i] = src[o*128 + c];
}

// ---------------- conv1x1 as register-tiled GEMM ----------------
// ASRC: 0 = planar f32 [c][px], 2 = item-major bf16 [bh][px][16]
// EPI : 0 = item-major f32 [bh][px][16], 1 = gelu planar f32, 2 = gate planar f32,
//       3 = v-epilogue: bf16 item-major always + f32 item-major if n==nearest(b)
template<int ASRC, int EPI>
__global__ __launch_bounds__(256, 3) void gemm1x1_k(const void* __restrict__ inp,
    const float* __restrict__ wt, const float* __restrict__ bias,
    float* __restrict__ outf, u16* __restrict__ out16,
    const float* __restrict__ gate, const float* __restrict__ relt)
{
  __shared__ __align__(16) float a_s[16*132];
  __shared__ __align__(16) float b_s[16*132];
  const int tid = threadIdx.x;
  const int tx = tid & 15, ty = tid >> 4;
  const int img = blockIdx.y;
  const int px0 = blockIdx.x * 128;
  const int sr = tid >> 4;
  const int sc = (tid & 15) * 8;

  float acc[64];
  #pragma unroll
  for (int oj = 0; oj < 8; ++oj) {
    float bv = bias[tx*8+oj];
    #pragma unroll
    for (int pi = 0; pi < 8; ++pi) acc[pi*8+oj] = bv;
  }

  for (int kc = 0; kc < 8; ++kc) {
    const int k0 = kc*16;
    { const float4* g = (const float4*)(wt + (k0+sr)*128 + sc);
      float4 v0 = g[0], v1 = g[1];
      *(float4*)&b_s[sr*132+sc] = v0; *(float4*)&b_s[sr*132+sc+4] = v1; }
    if (ASRC == 0) {
      const float* inf = (const float*)inp;
      const float4* g = (const float4*)(inf + (size_t)(img*128 + k0 + sr)*kHW + px0 + sc);
      float4 v0 = g[0], v1 = g[1];
      *(float4*)&a_s[sr*132+sc] = v0; *(float4*)&a_s[sr*132+sc+4] = v1;
    } else {
      const u16* g16 = (const u16*)inp;
      const int px = tid >> 1, hd0 = (tid & 1)*8;
      uint4 raw = *(const uint4*)(g16 + ((size_t)(img*8 + kc)*kHW + px0 + px)*16 + hd0);
      u32 w[4] = {raw.x, raw.y, raw.z, raw.w};
      #pragma unroll
      for (int gi = 0; gi < 4; ++gi) {
        a_s[(hd0+gi*2+0)*132+px] = __uint_as_float(w[gi]<<16);
        a_s[(hd0+gi*2+1)*132+px] = __uint_as_float(w[gi]&0xffff0000u);
      }
    }
    __syncthreads();
    #pragma unroll
    for (int k = 0; k < 16; ++k) {
      float4 b0 = *(const float4*)&b_s[k*132 + tx*8];
      float4 b1 = *(const float4*)&b_s[k*132 + tx*8 + 4];
      float4 a0 = *(const float4*)&a_s[k*132 + ty*8];
      float4 a1 = *(const float4*)&a_s[k*132 + ty*8 + 4];
      float av[8] = {a0.x,a0.y,a0.z,a0.w,a1.x,a1.y,a1.z,a1.w};
      float bv[8] = {b0.x,b0.y,b0.z,b0.w,b1.x,b1.y,b1.z,b1.w};
      #pragma unroll
      for (int pi = 0; pi < 8; ++pi)
        #pragma unroll
        for (int oj = 0; oj < 8; ++oj)
          acc[pi*8+oj] = fmaf(av[pi], bv[oj], acc[pi*8+oj]);
    }
    __syncthreads();
  }

  if (EPI == 0) {
    const int head = tx >> 1, hd0 = (tx & 1)*8;
    #pragma unroll
    for (int pi = 0; pi < 8; ++pi) {
      const int px = px0 + ty*8 + pi;
      float* dst = outf + ((size_t)(img*8 + head)*kHW + px)*16 + hd0;
      float4 t0 = {acc[pi*8+0],acc[pi*8+1],acc[pi*8+2],acc[pi*8+3]};
      float4 t1 = {acc[pi*8+4],acc[pi*8+5],acc[pi*8+6],acc[pi*8+7]};
      *(float4*)dst = t0; *(float4*)(dst+4) = t1;
    }
  } else if (EPI == 3) {
    const int b = img >> 2, n = img & 3;
    const int nidx = nearest_n(relt, b);
    const int head = tx >> 1, hd0 = (tx & 1)*8;
    #pragma unroll
    for (int pi = 0; pi < 8; ++pi) {
      const int px = px0 + ty*8 + pi;
      u16* d16 = out16 + ((size_t)(img*8 + head)*kHW + px)*16 + hd0;
      uint4 packed;
      packed.x = (u32)f2bf(acc[pi*8+0]) | ((u32)f2bf(acc[pi*8+1])<<16);
      packed.y = (u32)f2bf(acc[pi*8+2]) | ((u32)f2bf(acc[pi*8+3])<<16);
      packed.z = (u32)f2bf(acc[pi*8+4]) | ((u32)f2bf(acc[pi*8+5])<<16);
      packed.w = (u32)f2bf(acc[pi*8+6]) | ((u32)f2bf(acc[pi*8+7])<<16);
      *(uint4*)d16 = packed;
      if (n == nidx) {           // f32 copy of nearest image (for corr + GRU sampling)
        float* dst = outf + ((size_t)(b*8 + head)*kHW + px)*16 + hd0;
        float4 t0 = {acc[pi*8+0],acc[pi*8+1],acc[pi*8+2],acc[pi*8+3]};
        float4 t1 = {acc[pi*8+4],acc[pi*8+5],acc[pi*8+6],acc[pi*8+7]};
        *(float4*)dst = t0; *(float4*)(dst+4) = t1;
      }
    }
  } else {
    #pragma unroll
    for (int oj = 0; oj < 8; ++oj) {
      const int o = tx*8 + oj;
      float* dst = outf + (size_t)(img*128 + o)*kHW + px0 + ty*8;
      float v[8];
      #pragma unroll
      for (int pi = 0; pi < 8; ++pi) {
        float t = acc[pi*8+oj];
        v[pi] = (EPI == 1) ? gelu_f(t) : t * sigm_f(gate[o]);
      }
      float4 t0 = {v[0],v[1],v[2],v[3]};
      float4 t1 = {v[4],v[5],v[6],v[7]};
      *(float4*)dst = t0; *(float4*)(dst+4) = t1;
    }
  }
}

// ---------------- depthwise 7x7 + bias + exact gelu ----------------
__global__ __launch_bounds__(256) void dw_k(const float* __restrict__ q, const float* __restrict__ dww,
    const float* __restrict__ dwb, float* __restrict__ outf)
{
  int idx = blockIdx.x*256 + threadIdx.x;
  int px = idx % kHW;
  int bc = idx / kHW;
  int c = bc & 127;
  int x = px % 96, y = px / 96;
  float s = dwb[c];
  const float* qb = q + (size_t)bc*kHW;
  #pragma unroll
  for (int ky = 0; ky < 7; ++ky) {
    int yy = y + ky - 3;
    if (yy < 0 || yy > 95) continue;
    #pragma unroll
    for (int kx = 0; kx < 7; ++kx) {
      int xx = x + kx - 3;
      if (xx < 0 || xx > 95) continue;
      s = fmaf(qb[yy*96+xx], dww[c*49 + ky*7 + kx], s);
    }
  }
  outf[idx] = gelu_f(s);
}

// ---------------- time bias: (B,HEADS,N) ----------------
__global__ void tb_k(const float* __restrict__ te, const float* __restrict__ tw,
                     const float* __restrict__ tbias, float* __restrict__ tbb)
{
  int i = threadIdx.x;
  if (i >= 64) return;
  int b = i >> 5, h = (i >> 2) & 7, n = i & 3;
  float s = tbias[h];
  for (int tc = 0; tc < 64; ++tc) s = fmaf(te[(b*4+n)*64 + tc], tw[h*64+tc], s);
  tbb[(b*8+h)*4 + n] = s;
}

// ---------------- FUSED v5: r5/r8 structure + max memory-level parallelism ----------------
// Occupancy is grid-limited (2304 waves), so VGPRs are free: no min-wave bound, loads batched.
__global__ __launch_bounds__(256) void fused_k(
    const float* __restrict__ qb, const float* __restrict__ vf32, const u16* __restrict__ vb16,
    const float* __restrict__ netb, const float* __restrict__ relt,
    const float* __restrict__ wih, const float* __restrict__ whh,
    const float* __restrict__ bihp, const float* __restrict__ bhhp,
    const float* __restrict__ offw, const float* __restrict__ offbp,
    const float* __restrict__ aw, const float* __restrict__ abp,
    const float* __restrict__ tbb,
    u16* __restrict__ outattn16, float* __restrict__ entb)
{
  __shared__ __align__(16) float s_wih[48*20];   // rows padded 18->20 (pad=0)
  __shared__ __align__(16) float s_whh[48*16];
  __shared__ __align__(16) float s_offw[8*16];
  __shared__ __align__(16) float s_aw[4*16];
  __shared__ float s_bih[48], s_bhh[48], s_offb[8], s_ab[4];
  const int tid = threadIdx.x;
  for (int i = tid; i < 960; i += 256){ int g = i/20, k = i%20; s_wih[i] = (k<18)? wih[g*18+k] : 0.0f; }
  for (int i = tid; i < 768; i += 256) s_whh[i] = whh[i];
  if (tid < 128) s_offw[tid] = offw[tid];
  if (tid < 64)  s_aw[tid]  = aw[tid];
  if (tid < 48){ s_bih[tid] = bihp[tid]; s_bhh[tid] = bhhp[tid]; }
  if (tid < 8)   s_offb[tid] = offbp[tid];
  if (tid < 4)   s_ab[tid]  = abp[tid];

  // XCD swizzle (r5-validated): 576 blocks = 8 XCDs x 72
  const int vblk = (blockIdx.x & 7)*72 + (blockIdx.x >> 3);
  const int item = vblk*256 + tid;
  const int yx = item % kHW; const int bh = item / kHW;
  const int b = bh >> 3, head = bh & 7;
  const int x = yx % 96, y = yx / 96;
  const float* vp = vf32 + (size_t)(b*8 + head)*kM;   // nearest-n image, f32

  // ---- correlation argmax (f64, all 5 taps' loads hoisted via clamped addresses) ----
  float off_[8], attn_[4];
  {
    float qv[16];
    { const float4* q4 = (const float4*)(qb + (size_t)bh*kM + yx*16);
      #pragma unroll
      for (int g = 0; g < 4; ++g){ float4 t = q4[g]; qv[g*4]=t.x; qv[g*4+1]=t.y; qv[g*4+2]=t.z; qv[g*4+3]=t.w; } }
    const int sdx[5] = {0,-1,1,0,0};   // SHIFTS entries are (dx,dy)
    const int sdy[5] = {0,0,0,-1,1};
    float4 tv[5][4]; bool valid[5];
    #pragma unroll
    for (int s5 = 0; s5 < 5; ++s5) {
      int sy = y - sdy[s5], sx = x - sdx[s5];
      valid[s5] = (sy >= 0 && sy < 96 && sx >= 0 && sx < 96);
      int syc = min(max(sy,0),95), sxc = min(max(sx,0),95);
      const float4* tp = (const float4*)(vp + (syc*96+sxc)*16);
      tv[s5][0] = tp[0]; tv[s5][1] = tp[1]; tv[s5][2] = tp[2]; tv[s5][3] = tp[3];
    }
    double bsc = 0.0; int best = 0;
    #pragma unroll
    for (int s5 = 0; s5 < 5; ++s5) {
      double sc = 0.0;
      if (valid[s5]) {
        const float* tp = (const float*)&tv[s5][0];
        #pragma unroll
        for (int hd = 0; hd < 16; ++hd) sc += (double)qv[hd]*(double)tp[hd];
      }
      if (s5 == 0) { bsc = sc; best = 0; }
      else if (sc > bsc) { bsc = sc; best = s5; }
    }
    const float STEP = 2.0f/96.0f;
    float ox = 0.f, oy = 0.f;        // reference swap: x-offset = dy*2/W, y-offset = dx*2/H
    if (best == 3) ox = -STEP; else if (best == 4) ox = STEP;
    if (best == 1) oy = -STEP; else if (best == 2) oy = STEP;
    #pragma unroll
    for (int p = 0; p < 4; ++p) { off_[2*p] = ox; off_[2*p+1] = oy; attn_[p] = 0.0f; }
  }

  float h[16];
  { const float4* n4 = (const float4*)(netb + (size_t)item*16);
    #pragma unroll
    for (int g = 0; g < 4; ++g){ float4 t = n4[g]; h[g*4]=t.x; h[g*4+1]=t.y; h[g*4+2]=t.z; h[g*4+3]=t.w; } }

  __syncthreads();   // LDS weights ready

  // ---- 3 GRU refinement iterations, all state in registers (f32 sampling) ----
  for (int it = 0; it < 3; ++it) {
    const float p0x = off_[0];
    const float p0y = off_[1];
    Bilin bl = make_bilin(x, y, p0x, p0y);
    float xv[20];
    sample16(vp, bl, xv);
    xv[16] = p0x; xv[17] = p0y; xv[18] = 0.f; xv[19] = 0.f;

    float hn[16];
    #pragma unroll 2
    for (int j = 0; j < 16; ++j) {
      float g0 = s_bih[j], g1 = s_bih[16+j], g2 = s_bih[32+j];
      const float4* w0r = (const float4*)&s_wih[j*20];
      const float4* w1r = (const float4*)&s_wih[(16+j)*20];
      const float4* w2r = (const float4*)&s_wih[(32+j)*20];
      #pragma unroll
      for (int q4 = 0; q4 < 5; ++q4) {
        float4 w0 = w0r[q4], w1 = w1r[q4], w2 = w2r[q4];
        float a0 = xv[q4*4+0], a1 = xv[q4*4+1], a2 = xv[q4*4+2], a3 = xv[q4*4+3];
        g0 = fmaf(a0,w0.x,g0); g0 = fmaf(a1,w0.y,g0); g0 = fmaf(a2,w0.z,g0); g0 = fmaf(a3,w0.w,g0);
        g1 = fmaf(a0,w1.x,g1); g1 = fmaf(a1,w1.y,g1); g1 = fmaf(a2,w1.z,g1); g1 = fmaf(a3,w1.w,g1);
        g2 = fmaf(a0,w2.x,g2); g2 = fmaf(a1,w2.y,g2); g2 = fmaf(a2,w2.z,g2); g2 = fmaf(a3,w2.w,g2);
      }
      float t0 = s_bhh[j], t1 = s_bhh[16+j], t2 = s_bhh[32+j];
      const float4* h0r = (const float4*)&s_whh[j*16];
      const float4* h1r = (const float4*)&s_whh[(16+j)*16];
      const float4* h2r = (const float4*)&s_whh[(32+j)*16];
      #pragma unroll
      for (int q4 = 0; q4 < 4; ++q4) {
        float4 w0 = h0r[q4], w1 = h1r[q4], w2 = h2r[q4];
        float a0 = h[q4*4+0], a1 = h[q4*4+1], a2 = h[q4*4+2], a3 = h[q4*4+3];
        t0 = fmaf(a0,w0.x,t0); t0 = fmaf(a1,w0.y,t0); t0 = fmaf(a2,w0.z,t0); t0 = fmaf(a3,w0.w,t0);
        t1 = fmaf(a0,w1.x,t1); t1 = fmaf(a1,w1.y,t1); t1 = fmaf(a2,w1.z,t1); t1 = fmaf(a3,w1.w,t1);
        t2 = fmaf(a0,w2.x,t2); t2 = fmaf(a1,w2.y,t2); t2 = fmaf(a2,w2.z,t2); t2 = fmaf(a3,w2.w,t2);
      }
      float r = sigm_f(g0 + t0);
      float z = sigm_f(g1 + t1);
      float nn = tanhf(fmaf(r, t2, g2));
      hn[j] = fmaf(z, h[j], (1.0f - z)*nn);
    }
    #pragma unroll
    for (int j = 0; j < 16; ++j) h[j] = hn[j];

    #pragma unroll
    for (int d = 0; d < 8; ++d) {
      const float4* wr = (const float4*)&s_offw[d*16];
      float s = s_offb[d];
      #pragma unroll
      for (int q4 = 0; q4 < 4; ++q4) {
        float4 w4 = wr[q4];
        s = fmaf(h[q4*4+0], w4.x, s); s = fmaf(h[q4*4+1], w4.y, s);
        s = fmaf(h[q4*4+2], w4.z, s); s = fmaf(h[q4*4+3], w4.w, s);
      }
      off_[d] += s;
    }
    #pragma unroll
    for (int p = 0; p < 4; ++p) {
      const float4* wr = (const float4*)&s_aw[p*16];
      float s = s_ab[p];
      #pragma unroll
      for (int q4 = 0; q4 < 4; ++q4) {
        float4 w4 = wr[q4];
        s = fmaf(h[q4*4+0], w4.x, s); s = fmaf(h[q4*4+1], w4.y, s);
        s = fmaf(h[q4*4+2], w4.z, s); s = fmaf(h[q4*4+3], w4.w, s);
      }
      attn_[p] += s;
    }
  }

  // ---- softmax over (N,P) + entropy ----
  float lg[16];
  #pragma unroll
  for (int n = 0; n < 4; ++n) {
    float tv2 = tbb[(b*8+head)*4 + n];
    #pragma unroll
    for (int p = 0; p < 4; ++p) lg[n*4+p] = attn_[p] + tv2;
  }
  float mx = lg[0];
  #pragma unroll
  for (int i = 1; i < 16; ++i) mx = fmaxf(mx, lg[i]);
  float es = 0.f;
  #pragma unroll
  for (int i = 0; i < 16; ++i){ lg[i] = expf(lg[i]-mx); es += lg[i]; }
  float inv = 1.0f/es;
  float ent = 0.f;
  #pragma unroll
  for (int i = 0; i < 16; ++i){ lg[i] *= inv; ent -= lg[i]*logf(lg[i] + 1e-8f); }
  entb[item] = ent;

  // ---- N*P deformable sampling (bf16 v), p-outer n-inner, loads batched per p ----
  float acc[16];
  #pragma unroll
  for (int j = 0; j < 16; ++j) acc[j] = 0.f;
  #pragma unroll
  for (int p = 0; p < 4; ++p) {
    Bilin bl = make_bilin(x, y, off_[2*p], off_[2*p+1]);
    // hoist ALL 32 uint4 loads for the 4 n-streams before any unpack/FMA (max MLP)
    uint4 raw[4][8];
    #pragma unroll
    for (int n = 0; n < 4; ++n) {
      const u16* vpn = vb16 + (size_t)((b*4+n)*8 + head)*kM;
      raw[n][0] = *(const uint4*)(vpn + bl.i00); raw[n][1] = *(const uint4*)(vpn + bl.i00 + 8);
      raw[n][2] = *(const uint4*)(vpn + bl.i10); raw[n][3] = *(const uint4*)(vpn + bl.i10 + 8);
      raw[n][4] = *(const uint4*)(vpn + bl.i01); raw[n][5] = *(const uint4*)(vpn + bl.i01 + 8);
      raw[n][6] = *(const uint4*)(vpn + bl.i11); raw[n][7] = *(const uint4*)(vpn + bl.i11 + 8);
    }
    #pragma unroll
    for (int n = 0; n < 4; ++n) {
      u32 aw2[8] = {raw[n][0].x,raw[n][0].y,raw[n][0].z,raw[n][0].w, raw[n][1].x,raw[n][1].y,raw[n][1].z,raw[n][1].w};
      u32 bw2[8] = {raw[n][2].x,raw[n][2].y,raw[n][2].z,raw[n][2].w, raw[n][3].x,raw[n][3].y,raw[n][3].z,raw[n][3].w};
      u32 cw2[8] = {raw[n][4].x,raw[n][4].y,raw[n][4].z,raw[n][4].w, raw[n][5].x,raw[n][5].y,raw[n][5].z,raw[n][5].w};
      u32 dw2[8] = {raw[n][6].x,raw[n][6].y,raw[n][6].z,raw[n][6].w, raw[n][7].x,raw[n][7].y,raw[n][7].z,raw[n][7].w};
      float wnp = lg[n*4+p];
      #pragma unroll
      for (int g = 0; g < 8; ++g){
        float alo = __uint_as_float(aw2[g]<<16), ahi = __uint_as_float(aw2[g]&0xffff0000u);
        float blo = __uint_as_float(bw2[g]<<16), bhi = __uint_as_float(bw2[g]&0xffff0000u);
        float clo = __uint_as_float(cw2[g]<<16), chi = __uint_as_float(cw2[g]&0xffff0000u);
        float dlo = __uint_as_float(dw2[g]<<16), dhi = __uint_as_float(dw2[g]&0xffff0000u);
        float s0 = alo*bl.w00 + blo*bl.w10 + clo*bl.w01 + dlo*bl.w11;
        float s1 = ahi*bl.w00 + bhi*bl.w10 + chi*bl.w01 + dhi*bl.w11;
        acc[g*2+0] = fmaf(wnp, s0, acc[g*2+0]);
        acc[g*2+1] = fmaf(wnp, s1, acc[g*2+1]);
      }
    }
  }
  // bf16 item-major store (32 B contiguous per item)
  uint4 pk0, pk1;
  pk0.x = (u32)f2bf(acc[0])  | ((u32)f2bf(acc[1])<<16);
  pk0.y = (u32)f2bf(acc[2])  | ((u32)f2bf(acc[3])<<16);
  pk0.z = (u32)f2bf(acc[4])  | ((u32)f2bf(acc[5])<<16);
  pk0.w = (u32)f2bf(acc[6])  | ((u32)f2bf(acc[7])<<16);
  pk1.x = (u32)f2bf(acc[8])  | ((u32)f2bf(acc[9])<<16);
  pk1.y = (u32)f2bf(acc[10]) | ((u32)f2bf(acc[11])<<16);
  pk1.z = (u32)f2bf(acc[12]) | ((u32)f2bf(acc[13])<<16);
  pk1.w = (u32)f2bf(acc[14]) | ((u32)f2bf(acc[15])<<16);
  *(uint4*)(outattn16 + (size_t)item*16)     = pk0;
  *(uint4*)(outattn16 + (size_t)item*16 + 8) = pk1;
}

// ---------------- entropy mean over heads -> confidence/entropy outputs (f32) ----------------
__global__ __launch_bounds__(256) void ent_k(const float* __restrict__ entb, float* __restrict__ outf)
{
  int idx = blockIdx.x*256 + threadIdx.x;   // B*HW = 18432
  int b = idx / kHW, yx = idx % kHW;
  float s = 0.f;
  #pragma unroll
  for (int h8 = 0; h8 < 8; ++h8) s += entb[(b*8+h8)*kHW + yx];
  s *= 0.125f;
  float conf = 1.0f - fminf(fmaxf(s / (2.772588722239781f + 1e-8f), 0.0f), 1.0f);
  outf[2359296 + idx]         = conf;
  outf[2359296 + 18432 + idx] = s;
}

extern "C" void kernel_launch(void* const* d_in, const int* in_sizes, int n_in,
                              void* d_out, int out_size, void* d_ws, size_t ws_size,
                              hipStream_t stream)
{
  const float* query  = (const float*)d_in[0];
  const float* values = (const float*)d_in[1];
  const float* relt   = (const float*)d_in[2];
  const float* time_enc = (const float*)d_in[3];
  const float* qw  = (const float*)d_in[4];
  const float* qb  = (const float*)d_in[5];
  const float* vw  = (const float*)d_in[6];
  const float* vb  = (const float*)d_in[7];
  const float* dww = (const float*)d_in[8];
  const float* dwb = (const float*)d_in[9];
  const float* pww = (const float*)d_in[10];
  const float* pwb = (const float*)d_in[11];
  const float* wih = (const float*)d_in[12];
  const float* whh = (const float*)d_in[13];
  const float* bih = (const float*)d_in[14];
  const float* bhh = (const float*)d_in[15];
  const float* offw = (const float*)d_in[16];
  const float* offb = (const float*)d_in[17];
  const float* aw  = (const float*)d_in[18];
  const float* ab  = (const float*)d_in[19];
  const float* tw  = (const float*)d_in[20];
  const float* tb  = (const float*)d_in[21];
  const float* o1w = (const float*)d_in[22];
  const float* o1b = (const float*)d_in[23];
  const float* o2w = (const float*)d_in[24];
  const float* o2b = (const float*)d_in[25];
  const float* gate = (const float*)d_in[26];
  float* out = (float*)d_out;
  float* ws = (float*)d_ws;

  // workspace layout (f32 slots) — total 14385280 slots = 57.5 MB
  u16*   vb16   = (u16*)ws;                        // bf16 v, item-major [(b,n,h)][yx][16] : 4718592 fl
  float* vf32n  = ws + 4718592;                    // f32 v of nearest n [(b,h)][yx][16]   : 2359296
  float* qbuf   = ws + 7077888;                    // q item-major [(b,h)][yx][16]          : 2359296 ; reused as o1 mid (planar)
  float* netb   = ws + 9437184;                    // net item-major [bh][yx][16]           : 2359296
  float* dwbuf  = ws + 11796480;                   // dw mid planar [b][c][yx]              : 2359296 ; first half reused as outattn16
  u16*   oat16  = (u16*)dwbuf;                     // outattn bf16 [item][16]               : 2359296 u16
  float* entbf  = ws + 14155776;                   // per-head entropy                      :  147456
  float* tbbuf  = ws + 14303232;                   // time bias                             :      64
  float* wtbuf  = ws + 14303360;                   // 5 transposed weights                  :   81920
  if (ws_size < 14385280ull * 4ull) return;

  float* wt_q  = wtbuf;
  float* wt_v  = wtbuf + 16384;
  float* wt_pw = wtbuf + 32768;
  float* wt_o1 = wtbuf + 49152;
  float* wt_o2 = wtbuf + 65536;

  dim3 blk(256,1,1);
  // 0. transpose weights
  prep_k<<<dim3(64,5,1), blk, 0, stream>>>(qw, vw, pww, o1w, o2w, wtbuf);
  // 1. q = conv1x1(query) -> item-major f32 qbuf
  gemm1x1_k<0,0><<<dim3(72,2,1), blk, 0, stream>>>(query, wt_q, qb, qbuf, nullptr, nullptr, nullptr);
  // 2. depthwise 7x7 + gelu -> planar dwbuf
  dw_k<<<dim3(9216,1,1), blk, 0, stream>>>(query, dww, dwb, dwbuf);
  // 3. pointwise -> initial GRU state item-major netb (consumes dwbuf)
  gemm1x1_k<0,0><<<dim3(72,2,1), blk, 0, stream>>>(dwbuf, wt_pw, pwb, netb, nullptr, nullptr, nullptr);
  // 4. v = conv1x1(values) -> bf16 all + f32 nearest
  gemm1x1_k<0,3><<<dim3(72,8,1), blk, 0, stream>>>(values, wt_v, vb, vf32n, vb16, nullptr, relt);
  // 5. time bias
  tb_k<<<dim3(1,1,1), dim3(64,1,1), 0, stream>>>(time_enc, tw, tb, tbbuf);
  // 6. FUSED v5 (1 lane/item, batched-MLP sampling) -> oat16 (in dwbuf)
  fused_k<<<dim3(576,1,1), blk, 0, stream>>>(qbuf, vf32n, vb16, netb, relt,
                                             wih, whh, bih, bhh, offw, offb, aw, ab,
                                             tbbuf, oat16, entbf);
  // 7. entropy mean / confidence -> d_out tail (f32)
  ent_k<<<dim3(72,1,1), blk, 0, stream>>>(entbf, out);
  // 8. o1 + gelu: bf16 item-major oat16 -> planar f32 qbuf (mid)
  gemm1x1_k<2,1><<<dim3(72,2,1), blk, 0, stream>>>(oat16, wt_o1, o1b, qbuf, nullptr, nullptr, nullptr);
  // 9. o2 * sigmoid(gate): planar qbuf -> f32 d_out
  gemm1x1_k<0,2><<<dim3(72,2,1), blk, 0, stream>>>(qbuf, wt_o2, o2b, out, nullptr, gate, nullptr);
}

// Round 10
// 434.796 us; speedup vs baseline: 3.1658x; 1.0806x over previous
//
#include <hip/hip_runtime.h>
#include <hip/hip_bf16.h>

typedef unsigned short u16;
typedef unsigned int   u32;

// Problem constants: B=2, N=4, C=128, HEADS=8, P=4, H=W=96, TC=64, ITERS=3, HD=16
constexpr int kHW = 9216;       // 96*96
constexpr int kM  = 147456;     // 16*9216 (item-major image stride; also B*HEADS*HW items)

__device__ __forceinline__ float gelu_f(float v){ return 0.5f*v*(1.0f+erff(v*0.70710678118654752f)); }
__device__ __forceinline__ float sigm_f(float v){ return 1.0f/(1.0f+expf(-v)); }
__device__ __forceinline__ u16 f2bf(float f){
  u32 x = __float_as_uint(f);
  return (u16)((x + 0x7fffu + ((x>>16)&1u)) >> 16);   // RNE
}
__device__ __forceinline__ int nearest_n(const float* __restrict__ relt, int b){
  int nidx = 0; float bv = fabsf(relt[b*4]);
  for (int n = 1; n < 4; ++n){ float a = fabsf(relt[b*4+n]); if (a < bv){ bv=a; nidx=n; } }
  return nidx;
}

struct Bilin { int i00,i10,i01,i11; float w00,w10,w01,w11; };

__device__ __forceinline__ Bilin make_bilin(int x, int y, float ox, float oy){
  float gx = fmaf((float)x, 2.0f/95.0f, -1.0f);
  float gy = fmaf((float)y, 2.0f/95.0f, -1.0f);
  float sgx = fminf(fmaxf(gx+ox,-1.0f),1.0f);
  float sgy = fminf(fmaxf(gy+oy,-1.0f),1.0f);
  float ix = (sgx+1.0f)*0.5f*95.0f;
  float iy = (sgy+1.0f)*0.5f*95.0f;
  float x0f = floorf(ix), y0f = floorf(iy);
  float wx = ix-x0f, wy = iy-y0f;
  int x0 = min(max((int)x0f,0),95), y0 = min(max((int)y0f,0),95);
  int x1 = min(x0+1,95), y1 = min(y0+1,95);
  Bilin b;
  b.i00=(y0*96+x0)*16; b.i10=(y0*96+x1)*16; b.i01=(y1*96+x0)*16; b.i11=(y1*96+x1)*16;
  float iwx=1.0f-wx, iwy=1.0f-wy;
  b.w00=iwx*iwy; b.w10=wx*iwy; b.w01=iwx*wy; b.w11=wx*wy;
  return b;
}

__device__ __forceinline__ void sample16(const float* __restrict__ vp, const Bilin& bl, float* __restrict__ o){
  const float4* p00 = (const float4*)(vp + bl.i00);
  const float4* p10 = (const float4*)(vp + bl.i10);
  const float4* p01 = (const float4*)(vp + bl.i01);
  const float4* p11 = (const float4*)(vp + bl.i11);
  #pragma unroll
  for (int g = 0; g < 4; ++g){
    float4 a=p00[g], b=p10[g], c=p01[g], d=p11[g];
    o[g*4+0] = a.x*bl.w00 + b.x*bl.w10 + c.x*bl.w01 + d.x*bl.w11;
    o[g*4+1] = a.y*bl.w00 + b.y*bl.w10 + c.y*bl.w01 + d.y*bl.w11;
    o[g*4+2] = a.z*bl.w00 + b.z*bl.w10 + c.z*bl.w01 + d.z*bl.w11;
    o[g*4+3] = a.w*bl.w00 + b.w*bl.w10 + c.w*bl.w01 + d.w*bl.w11;
  }
}

// ---------------- transpose the five (C,C) weight matrices into [c][o] f32 ----------------
__global__ __launch_bounds__(256) void prep_k(const float* __restrict__ qw, const float* __restrict__ vw,
    const float* __restrict__ pww, const float* __restrict__ o1w, const float* __restrict__ o2w,
    float* __restrict__ wt)
{
  const float* src = (blockIdx.y==0)?qw:(blockIdx.y==1)?vw:(blockIdx.y==2)?pww:(blockIdx.y==3)?o1w:o2w;
  float* d = wt + blockIdx.y*16384;
  int i = blockIdx.x*256 + threadIdx.x;
  int o = i & 127, c = i >> 7;
  d[i] = src[o*128 + c];
}

// ---------------- MEGA-GEMM: q (y=0,1) + v (y=2..9) + pw (y=10,11) in one launch ----------
// 864 blocks = 3456 waves = 3.4/SIMD. Same tile/math as r9 gemm1x1_k (bitwise identical).
__global__ __launch_bounds__(256, 3) void gemm_qvp_k(
    const float* __restrict__ query, const float* __restrict__ values, const float* __restrict__ dwbuf,
    const float* __restrict__ wtb,
    const float* __restrict__ qb2, const float* __restrict__ vb2, const float* __restrict__ pwb2,
    float* __restrict__ qbuf, float* __restrict__ netb,
    float* __restrict__ vf32n, u16* __restrict__ vb16, const float* __restrict__ relt)
{
  __shared__ __align__(16) float a_s[16*132];
  __shared__ __align__(16) float b_s[16*132];
  const int tid = threadIdx.x;
  const int tx = tid & 15, ty = tid >> 4;
  const int iy = blockIdx.y;
  const float* inp; const float* wt; const float* bias; int img; int mode;
  if (iy < 2)       { inp = query;  wt = wtb;         bias = qb2;  img = iy;      mode = 0; }
  else if (iy < 10) { inp = values; wt = wtb + 16384; bias = vb2;  img = iy - 2;  mode = 1; }
  else              { inp = dwbuf;  wt = wtb + 32768; bias = pwb2; img = iy - 10; mode = 2; }
  const int px0 = blockIdx.x * 128;
  const int sr = tid >> 4;
  const int sc = (tid & 15) * 8;

  float acc[64];
  #pragma unroll
  for (int oj = 0; oj < 8; ++oj) {
    float bv = bias[tx*8+oj];
    #pragma unroll
    for (int pi = 0; pi < 8; ++pi) acc[pi*8+oj] = bv;
  }

  for (int kc = 0; kc < 8; ++kc) {
    const int k0 = kc*16;
    { const float4* g = (const float4*)(wt + (k0+sr)*128 + sc);
      float4 v0 = g[0], v1 = g[1];
      *(float4*)&b_s[sr*132+sc] = v0; *(float4*)&b_s[sr*132+sc+4] = v1; }
    { const float4* g = (const float4*)(inp + (size_t)(img*128 + k0 + sr)*kHW + px0 + sc);
      float4 v0 = g[0], v1 = g[1];
      *(float4*)&a_s[sr*132+sc] = v0; *(float4*)&a_s[sr*132+sc+4] = v1; }
    __syncthreads();
    #pragma unroll
    for (int k = 0; k < 16; ++k) {
      float4 b0 = *(const float4*)&b_s[k*132 + tx*8];
      float4 b1 = *(const float4*)&b_s[k*132 + tx*8 + 4];
      float4 a0 = *(const float4*)&a_s[k*132 + ty*8];
      float4 a1 = *(const float4*)&a_s[k*132 + ty*8 + 4];
      float av[8] = {a0.x,a0.y,a0.z,a0.w,a1.x,a1.y,a1.z,a1.w};
      float bv[8] = {b0.x,b0.y,b0.z,b0.w,b1.x,b1.y,b1.z,b1.w};
      #pragma unroll
      for (int pi = 0; pi < 8; ++pi)
        #pragma unroll
        for (int oj = 0; oj < 8; ++oj)
          acc[pi*8+oj] = fmaf(av[pi], bv[oj], acc[pi*8+oj]);
    }
    __syncthreads();
  }

  const int head = tx >> 1, hd0 = (tx & 1)*8;
  if (mode == 1) {
    const int b = img >> 2, n = img & 3;
    const int nidx = nearest_n(relt, b);
    #pragma unroll
    for (int pi = 0; pi < 8; ++pi) {
      const int px = px0 + ty*8 + pi;
      u16* d16 = vb16 + ((size_t)(img*8 + head)*kHW + px)*16 + hd0;
      uint4 packed;
      packed.x = (u32)f2bf(acc[pi*8+0]) | ((u32)f2bf(acc[pi*8+1])<<16);
      packed.y = (u32)f2bf(acc[pi*8+2]) | ((u32)f2bf(acc[pi*8+3])<<16);
      packed.z = (u32)f2bf(acc[pi*8+4]) | ((u32)f2bf(acc[pi*8+5])<<16);
      packed.w = (u32)f2bf(acc[pi*8+6]) | ((u32)f2bf(acc[pi*8+7])<<16);
      *(uint4*)d16 = packed;
      if (n == nidx) {           // f32 copy of nearest image (for corr + GRU sampling)
        float* dst = vf32n + ((size_t)(b*8 + head)*kHW + px)*16 + hd0;
        float4 t0 = {acc[pi*8+0],acc[pi*8+1],acc[pi*8+2],acc[pi*8+3]};
        float4 t1 = {acc[pi*8+4],acc[pi*8+5],acc[pi*8+6],acc[pi*8+7]};
        *(float4*)dst = t0; *(float4*)(dst+4) = t1;
      }
    }
  } else {
    float* outf = (mode == 0) ? qbuf : netb;
    #pragma unroll
    for (int pi = 0; pi < 8; ++pi) {
      const int px = px0 + ty*8 + pi;
      float* dst = outf + ((size_t)(img*8 + head)*kHW + px)*16 + hd0;
      float4 t0 = {acc[pi*8+0],acc[pi*8+1],acc[pi*8+2],acc[pi*8+3]};
      float4 t1 = {acc[pi*8+4],acc[pi*8+5],acc[pi*8+6],acc[pi*8+7]};
      *(float4*)dst = t0; *(float4*)(dst+4) = t1;
    }
  }
}

// ---------------- fused o1(gelu) -> o2(gate) : mid kept in LDS ----------------
__global__ __launch_bounds__(256) void o1o2_k(const u16* __restrict__ oat,
    const float* __restrict__ wt1, const float* __restrict__ o1b,
    const float* __restrict__ wt2, const float* __restrict__ o2b,
    const float* __restrict__ gate, float* __restrict__ out)
{
  __shared__ __align__(16) float a_s[16*132];
  __shared__ __align__(16) float b_s[16*132];
  __shared__ __align__(16) float mid[128*132];   // 67.6 KB
  const int tid = threadIdx.x;
  const int tx = tid & 15, ty = tid >> 4;
  const int img = blockIdx.y;
  const int px0 = blockIdx.x * 128;
  const int sr = tid >> 4;
  const int sc = (tid & 15) * 8;

  float acc[64];
  // ---- stage 1: o1 GEMM (bf16 item-major input), bias-first k-ascending ----
  #pragma unroll
  for (int oj = 0; oj < 8; ++oj) {
    float bv = o1b[tx*8+oj];
    #pragma unroll
    for (int pi = 0; pi < 8; ++pi) acc[pi*8+oj] = bv;
  }
  for (int kc = 0; kc < 8; ++kc) {
    const int k0 = kc*16;
    { const float4* g = (const float4*)(wt1 + (k0+sr)*128 + sc);
      float4 v0 = g[0], v1 = g[1];
      *(float4*)&b_s[sr*132+sc] = v0; *(float4*)&b_s[sr*132+sc+4] = v1; }
    { const int px = tid >> 1, hd0 = (tid & 1)*8;
      uint4 raw = *(const uint4*)(oat + ((size_t)(img*8 + kc)*kHW + px0 + px)*16 + hd0);
      u32 w[4] = {raw.x, raw.y, raw.z, raw.w};
      #pragma unroll
      for (int gi = 0; gi < 4; ++gi) {
        a_s[(hd0+gi*2+0)*132+px] = __uint_as_float(w[gi]<<16);
        a_s[(hd0+gi*2+1)*132+px] = __uint_as_float(w[gi]&0xffff0000u);
      }
    }
    __syncthreads();
    #pragma unroll
    for (int k = 0; k < 16; ++k) {
      float4 b0 = *(const float4*)&b_s[k*132 + tx*8];
      float4 b1 = *(const float4*)&b_s[k*132 + tx*8 + 4];
      float4 a0 = *(const float4*)&a_s[k*132 + ty*8];
      float4 a1 = *(const float4*)&a_s[k*132 + ty*8 + 4];
      float av[8] = {a0.x,a0.y,a0.z,a0.w,a1.x,a1.y,a1.z,a1.w};
      float bv[8] = {b0.x,b0.y,b0.z,b0.w,b1.x,b1.y,b1.z,b1.w};
      #pragma unroll
      for (int pi = 0; pi < 8; ++pi)
        #pragma unroll
        for (int oj = 0; oj < 8; ++oj)
          acc[pi*8+oj] = fmaf(av[pi], bv[oj], acc[pi*8+oj]);
    }
    __syncthreads();
  }
  // gelu -> mid (planar [ch][px_local])
  #pragma unroll
  for (int oj = 0; oj < 8; ++oj)
    #pragma unroll
    for (int pi = 0; pi < 8; ++pi)
      mid[(tx*8+oj)*132 + ty*8+pi] = gelu_f(acc[pi*8+oj]);
  __syncthreads();

  // ---- stage 2: o2 GEMM, A read directly from LDS mid ----
  #pragma unroll
  for (int oj = 0; oj < 8; ++oj) {
    float bv = o2b[tx*8+oj];
    #pragma unroll
    for (int pi = 0; pi < 8; ++pi) acc[pi*8+oj] = bv;
  }
  for (int kc = 0; kc < 8; ++kc) {
    const int k0 = kc*16;
    { const float4* g = (const float4*)(wt2 + (k0+sr)*128 + sc);
      float4 v0 = g[0], v1 = g[1];
      *(float4*)&b_s[sr*132+sc] = v0; *(float4*)&b_s[sr*132+sc+4] = v1; }
    __syncthreads();
    #pragma unroll
    for (int k = 0; k < 16; ++k) {
      float4 b0 = *(const float4*)&b_s[k*132 + tx*8];
      float4 b1 = *(const float4*)&b_s[k*132 + tx*8 + 4];
      float4 a0 = *(const float4*)&mid[(k0+k)*132 + ty*8];
      float4 a1 = *(const float4*)&mid[(k0+k)*132 + ty*8 + 4];
      float av[8] = {a0.x,a0.y,a0.z,a0.w,a1.x,a1.y,a1.z,a1.w};
      float bv[8] = {b0.x,b0.y,b0.z,b0.w,b1.x,b1.y,b1.z,b1.w};
      #pragma unroll
      for (int pi = 0; pi < 8; ++pi)
        #pragma unroll
        for (int oj = 0; oj < 8; ++oj)
          acc[pi*8+oj] = fmaf(av[pi], bv[oj], acc[pi*8+oj]);
    }
    __syncthreads();
  }
  #pragma unroll
  for (int oj = 0; oj < 8; ++oj) {
    const int o = tx*8 + oj;
    float* dst = out + (size_t)(img*128 + o)*kHW + px0 + ty*8;
    float sg = sigm_f(gate[o]);
    float v[8];
    #pragma unroll
    for (int pi = 0; pi < 8; ++pi) v[pi] = acc[pi*8+oj] * sg;
    float4 t0 = {v[0],v[1],v[2],v[3]};
    float4 t1 = {v[4],v[5],v[6],v[7]};
    *(float4*)dst = t0; *(float4*)(dst+4) = t1;
  }
}

// ---------------- depthwise 7x7 + bias + exact gelu ----------------
__global__ __launch_bounds__(256) void dw_k(const float* __restrict__ q, const float* __restrict__ dww,
    const float* __restrict__ dwb, float* __restrict__ outf)
{
  int idx = blockIdx.x*256 + threadIdx.x;
  int px = idx % kHW;
  int bc = idx / kHW;
  int c = bc & 127;
  int x = px % 96, y = px / 96;
  float s = dwb[c];
  const float* qb = q + (size_t)bc*kHW;
  #pragma unroll
  for (int ky = 0; ky < 7; ++ky) {
    int yy = y + ky - 3;
    if (yy < 0 || yy > 95) continue;
    #pragma unroll
    for (int kx = 0; kx < 7; ++kx) {
      int xx = x + kx - 3;
      if (xx < 0 || xx > 95) continue;
      s = fmaf(qb[yy*96+xx], dww[c*49 + ky*7 + kx], s);
    }
  }
  outf[idx] = gelu_f(s);
}

// ---------------- time bias: (B,HEADS,N) ----------------
__global__ void tb_k(const float* __restrict__ te, const float* __restrict__ tw,
                     const float* __restrict__ tbias, float* __restrict__ tbb)
{
  int i = threadIdx.x;
  if (i >= 64) return;
  int b = i >> 5, h = (i >> 2) & 7, n = i & 3;
  float s = tbias[h];
  for (int tc = 0; tc < 64; ++tc) s = fmaf(te[(b*4+n)*64 + tc], tw[h*64+tc], s);
  tbb[(b*8+h)*4 + n] = s;
}

// ---------------- FUSED v5 (r9, unchanged): 1 lane/item + max MLP ----------------
__global__ __launch_bounds__(256) void fused_k(
    const float* __restrict__ qb, const float* __restrict__ vf32, const u16* __restrict__ vb16,
    const float* __restrict__ netb, const float* __restrict__ relt,
    const float* __restrict__ wih, const float* __restrict__ whh,
    const float* __restrict__ bihp, const float* __restrict__ bhhp,
    const float* __restrict__ offw, const float* __restrict__ offbp,
    const float* __restrict__ aw, const float* __restrict__ abp,
    const float* __restrict__ tbb,
    u16* __restrict__ outattn16, float* __restrict__ entb)
{
  __shared__ __align__(16) float s_wih[48*20];   // rows padded 18->20 (pad=0)
  __shared__ __align__(16) float s_whh[48*16];
  __shared__ __align__(16) float s_offw[8*16];
  __shared__ __align__(16) float s_aw[4*16];
  __shared__ float s_bih[48], s_bhh[48], s_offb[8], s_ab[4];
  const int tid = threadIdx.x;
  for (int i = tid; i < 960; i += 256){ int g = i/20, k = i%20; s_wih[i] = (k<18)? wih[g*18+k] : 0.0f; }
  for (int i = tid; i < 768; i += 256) s_whh[i] = whh[i];
  if (tid < 128) s_offw[tid] = offw[tid];
  if (tid < 64)  s_aw[tid]  = aw[tid];
  if (tid < 48){ s_bih[tid] = bihp[tid]; s_bhh[tid] = bhhp[tid]; }
  if (tid < 8)   s_offb[tid] = offbp[tid];
  if (tid < 4)   s_ab[tid]  = abp[tid];

  // XCD swizzle (r5-validated): 576 blocks = 8 XCDs x 72
  const int vblk = (blockIdx.x & 7)*72 + (blockIdx.x >> 3);
  const int item = vblk*256 + tid;
  const int yx = item % kHW; const int bh = item / kHW;
  const int b = bh >> 3, head = bh & 7;
  const int x = yx % 96, y = yx / 96;
  const float* vp = vf32 + (size_t)(b*8 + head)*kM;   // nearest-n image, f32

  // ---- correlation argmax (f64, all 5 taps' loads hoisted via clamped addresses) ----
  float off_[8], attn_[4];
  {
    float qv[16];
    { const float4* q4 = (const float4*)(qb + (size_t)bh*kM + yx*16);
      #pragma unroll
      for (int g = 0; g < 4; ++g){ float4 t = q4[g]; qv[g*4]=t.x; qv[g*4+1]=t.y; qv[g*4+2]=t.z; qv[g*4+3]=t.w; } }
    const int sdx[5] = {0,-1,1,0,0};   // SHIFTS entries are (dx,dy)
    const int sdy[5] = {0,0,0,-1,1};
    float4 tv[5][4]; bool valid[5];
    #pragma unroll
    for (int s5 = 0; s5 < 5; ++s5) {
      int sy = y - sdy[s5], sx = x - sdx[s5];
      valid[s5] = (sy >= 0 && sy < 96 && sx >= 0 && sx < 96);
      int syc = min(max(sy,0),95), sxc = min(max(sx,0),95);
      const float4* tp = (const float4*)(vp + (syc*96+sxc)*16);
      tv[s5][0] = tp[0]; tv[s5][1] = tp[1]; tv[s5][2] = tp[2]; tv[s5][3] = tp[3];
    }
    double bsc = 0.0; int best = 0;
    #pragma unroll
    for (int s5 = 0; s5 < 5; ++s5) {
      double sc = 0.0;
      if (valid[s5]) {
        const float* tp = (const float*)&tv[s5][0];
        #pragma unroll
        for (int hd = 0; hd < 16; ++hd) sc += (double)qv[hd]*(double)tp[hd];
      }
      if (s5 == 0) { bsc = sc; best = 0; }
      else if (sc > bsc) { bsc = sc; best = s5; }
    }
    const float STEP = 2.0f/96.0f;
    float ox = 0.f, oy = 0.f;        // reference swap: x-offset = dy*2/W, y-offset = dx*2/H
    if (best == 3) ox = -STEP; else if (best == 4) ox = STEP;
    if (best == 1) oy = -STEP; else if (best == 2) oy = STEP;
    #pragma unroll
    for (int p = 0; p < 4; ++p) { off_[2*p] = ox; off_[2*p+1] = oy; attn_[p] = 0.0f; }
  }

  float h[16];
  { const float4* n4 = (const float4*)(netb + (size_t)item*16);
    #pragma unroll
    for (int g = 0; g < 4; ++g){ float4 t = n4[g]; h[g*4]=t.x; h[g*4+1]=t.y; h[g*4+2]=t.z; h[g*4+3]=t.w; } }

  __syncthreads();   // LDS weights ready

  // ---- 3 GRU refinement iterations, all state in registers (f32 sampling) ----
  for (int it = 0; it < 3; ++it) {
    const float p0x = off_[0];
    const float p0y = off_[1];
    Bilin bl = make_bilin(x, y, p0x, p0y);
    float xv[20];
    sample16(vp, bl, xv);
    xv[16] = p0x; xv[17] = p0y; xv[18] = 0.f; xv[19] = 0.f;

    float hn[16];
    #pragma unroll 2
    for (int j = 0; j < 16; ++j) {
      float g0 = s_bih[j], g1 = s_bih[16+j], g2 = s_bih[32+j];
      const float4* w0r = (const float4*)&s_wih[j*20];
      const float4* w1r = (const float4*)&s_wih[(16+j)*20];
      const float4* w2r = (const float4*)&s_wih[(32+j)*20];
      #pragma unroll
      for (int q4 = 0; q4 < 5; ++q4) {
        float4 w0 = w0r[q4], w1 = w1r[q4], w2 = w2r[q4];
        float a0 = xv[q4*4+0], a1 = xv[q4*4+1], a2 = xv[q4*4+2], a3 = xv[q4*4+3];
        g0 = fmaf(a0,w0.x,g0); g0 = fmaf(a1,w0.y,g0); g0 = fmaf(a2,w0.z,g0); g0 = fmaf(a3,w0.w,g0);
        g1 = fmaf(a0,w1.x,g1); g1 = fmaf(a1,w1.y,g1); g1 = fmaf(a2,w1.z,g1); g1 = fmaf(a3,w1.w,g1);
        g2 = fmaf(a0,w2.x,g2); g2 = fmaf(a1,w2.y,g2); g2 = fmaf(a2,w2.z,g2); g2 = fmaf(a3,w2.w,g2);
      }
      float t0 = s_bhh[j], t1 = s_bhh[16+j], t2 = s_bhh[32+j];
      const float4* h0r = (const float4*)&s_whh[j*16];
      const float4* h1r = (const float4*)&s_whh[(16+j)*16];
      const float4* h2r = (const float4*)&s_whh[(32+j)*16];
      #pragma unroll
      for (int q4 = 0; q4 < 4; ++q4) {
        float4 w0 = h0r[q4], w1 = h1r[q4], w2 = h2r[q4];
        float a0 = h[q4*4+0], a1 = h[q4*4+1], a2 = h[q4*4+2], a3 = h[q4*4+3];
        t0 = fmaf(a0,w0.x,t0); t0 = fmaf(a1,w0.y,t0); t0 = fmaf(a2,w0.z,t0); t0 = fmaf(a3,w0.w,t0);
        t1 = fmaf(a0,w1.x,t1); t1 = fmaf(a1,w1.y,t1); t1 = fmaf(a2,w1.z,t1); t1 = fmaf(a3,w1.w,t1);
        t2 = fmaf(a0,w2.x,t2); t2 = fmaf(a1,w2.y,t2); t2 = fmaf(a2,w2.z,t2); t2 = fmaf(a3,w2.w,t2);
      }
      float r = sigm_f(g0 + t0);
      float z = sigm_f(g1 + t1);
      float nn = tanhf(fmaf(r, t2, g2));
      hn[j] = fmaf(z, h[j], (1.0f - z)*nn);
    }
    #pragma unroll
    for (int j = 0; j < 16; ++j) h[j] = hn[j];

    #pragma unroll
    for (int d = 0; d < 8; ++d) {
      const float4* wr = (const float4*)&s_offw[d*16];
      float s = s_offb[d];
      #pragma unroll
      for (int q4 = 0; q4 < 4; ++q4) {
        float4 w4 = wr[q4];
        s = fmaf(h[q4*4+0], w4.x, s); s = fmaf(h[q4*4+1], w4.y, s);
        s = fmaf(h[q4*4+2], w4.z, s); s = fmaf(h[q4*4+3], w4.w, s);
      }
      off_[d] += s;
    }
    #pragma unroll
    for (int p = 0; p < 4; ++p) {
      const float4* wr = (const float4*)&s_aw[p*16];
      float s = s_ab[p];
      #pragma unroll
      for (int q4 = 0; q4 < 4; ++q4) {
        float4 w4 = wr[q4];
        s = fmaf(h[q4*4+0], w4.x, s); s = fmaf(h[q4*4+1], w4.y, s);
        s = fmaf(h[q4*4+2], w4.z, s); s = fmaf(h[q4*4+3], w4.w, s);
      }
      attn_[p] += s;
    }
  }

  // ---- softmax over (N,P) + entropy ----
  float lg[16];
  #pragma unroll
  for (int n = 0; n < 4; ++n) {
    float tv2 = tbb[(b*8+head)*4 + n];
    #pragma unroll
    for (int p = 0; p < 4; ++p) lg[n*4+p] = attn_[p] + tv2;
  }
  float mx = lg[0];
  #pragma unroll
  for (int i = 1; i < 16; ++i) mx = fmaxf(mx, lg[i]);
  float es = 0.f;
  #pragma unroll
  for (int i = 0; i < 16; ++i){ lg[i] = expf(lg[i]-mx); es += lg[i]; }
  float inv = 1.0f/es;
  float ent = 0.f;
  #pragma unroll
  for (int i = 0; i < 16; ++i){ lg[i] *= inv; ent -= lg[i]*logf(lg[i] + 1e-8f); }
  entb[item] = ent;

  // ---- N*P deformable sampling (bf16 v), p-outer n-inner, loads batched per p ----
  float acc[16];
  #pragma unroll
  for (int j = 0; j < 16; ++j) acc[j] = 0.f;
  #pragma unroll
  for (int p = 0; p < 4; ++p) {
    Bilin bl = make_bilin(x, y, off_[2*p], off_[2*p+1]);
    uint4 raw[4][8];
    #pragma unroll
    for (int n = 0; n < 4; ++n) {
      const u16* vpn = vb16 + (size_t)((b*4+n)*8 + head)*kM;
      raw[n][0] = *(const uint4*)(vpn + bl.i00); raw[n][1] = *(const uint4*)(vpn + bl.i00 + 8);
      raw[n][2] = *(const uint4*)(vpn + bl.i10); raw[n][3] = *(const uint4*)(vpn + bl.i10 + 8);
      raw[n][4] = *(const uint4*)(vpn + bl.i01); raw[n][5] = *(const uint4*)(vpn + bl.i01 + 8);
      raw[n][6] = *(const uint4*)(vpn + bl.i11); raw[n][7] = *(const uint4*)(vpn + bl.i11 + 8);
    }
    #pragma unroll
    for (int n = 0; n < 4; ++n) {
      u32 aw2[8] = {raw[n][0].x,raw[n][0].y,raw[n][0].z,raw[n][0].w, raw[n][1].x,raw[n][1].y,raw[n][1].z,raw[n][1].w};
      u32 bw2[8] = {raw[n][2].x,raw[n][2].y,raw[n][2].z,raw[n][2].w, raw[n][3].x,raw[n][3].y,raw[n][3].z,raw[n][3].w};
      u32 cw2[8] = {raw[n][4].x,raw[n][4].y,raw[n][4].z,raw[n][4].w, raw[n][5].x,raw[n][5].y,raw[n][5].z,raw[n][5].w};
      u32 dw2[8] = {raw[n][6].x,raw[n][6].y,raw[n][6].z,raw[n][6].w, raw[n][7].x,raw[n][7].y,raw[n][7].z,raw[n][7].w};
      float wnp = lg[n*4+p];
      #pragma unroll
      for (int g = 0; g < 8; ++g){
        float alo = __uint_as_float(aw2[g]<<16), ahi = __uint_as_float(aw2[g]&0xffff0000u);
        float blo = __uint_as_float(bw2[g]<<16), bhi = __uint_as_float(bw2[g]&0xffff0000u);
        float clo = __uint_as_float(cw2[g]<<16), chi = __uint_as_float(cw2[g]&0xffff0000u);
        float dlo = __uint_as_float(dw2[g]<<16), dhi = __uint_as_float(dw2[g]&0xffff0000u);
        float s0 = alo*bl.w00 + blo*bl.w10 + clo*bl.w01 + dlo*bl.w11;
        float s1 = ahi*bl.w00 + bhi*bl.w10 + chi*bl.w01 + dhi*bl.w11;
        acc[g*2+0] = fmaf(wnp, s0, acc[g*2+0]);
        acc[g*2+1] = fmaf(wnp, s1, acc[g*2+1]);
      }
    }
  }
  uint4 pk0, pk1;
  pk0.x = (u32)f2bf(acc[0])  | ((u32)f2bf(acc[1])<<16);
  pk0.y = (u32)f2bf(acc[2])  | ((u32)f2bf(acc[3])<<16);
  pk0.z = (u32)f2bf(acc[4])  | ((u32)f2bf(acc[5])<<16);
  pk0.w = (u32)f2bf(acc[6])  | ((u32)f2bf(acc[7])<<16);
  pk1.x = (u32)f2bf(acc[8])  | ((u32)f2bf(acc[9])<<16);
  pk1.y = (u32)f2bf(acc[10]) | ((u32)f2bf(acc[11])<<16);
  pk1.z = (u32)f2bf(acc[12]) | ((u32)f2bf(acc[13])<<16);
  pk1.w = (u32)f2bf(acc[14]) | ((u32)f2bf(acc[15])<<16);
  *(uint4*)(outattn16 + (size_t)item*16)     = pk0;
  *(uint4*)(outattn16 + (size_t)item*16 + 8) = pk1;
}

// ---------------- entropy mean over heads -> confidence/entropy outputs (f32) ----------------
__global__ __launch_bounds__(256) void ent_k(const float* __restrict__ entb, float* __restrict__ outf)
{
  int idx = blockIdx.x*256 + threadIdx.x;   // B*HW = 18432
  int b = idx / kHW, yx = idx % kHW;
  float s = 0.f;
  #pragma unroll
  for (int h8 = 0; h8 < 8; ++h8) s += entb[(b*8+h8)*kHW + yx];
  s *= 0.125f;
  float conf = 1.0f - fminf(fmaxf(s / (2.772588722239781f + 1e-8f), 0.0f), 1.0f);
  outf[2359296 + idx]         = conf;
  outf[2359296 + 18432 + idx] = s;
}

extern "C" void kernel_launch(void* const* d_in, const int* in_sizes, int n_in,
                              void* d_out, int out_size, void* d_ws, size_t ws_size,
                              hipStream_t stream)
{
  const float* query  = (const float*)d_in[0];
  const float* values = (const float*)d_in[1];
  const float* relt   = (const float*)d_in[2];
  const float* time_enc = (const float*)d_in[3];
  const float* qw  = (const float*)d_in[4];
  const float* qb  = (const float*)d_in[5];
  const float* vw  = (const float*)d_in[6];
  const float* vb  = (const float*)d_in[7];
  const float* dww = (const float*)d_in[8];
  const float* dwb = (const float*)d_in[9];
  const float* pww = (const float*)d_in[10];
  const float* pwb = (const float*)d_in[11];
  const float* wih = (const float*)d_in[12];
  const float* whh = (const float*)d_in[13];
  const float* bih = (const float*)d_in[14];
  const float* bhh = (const float*)d_in[15];
  const float* offw = (const float*)d_in[16];
  const float* offb = (const float*)d_in[17];
  const float* aw  = (const float*)d_in[18];
  const float* ab  = (const float*)d_in[19];
  const float* tw  = (const float*)d_in[20];
  const float* tb  = (const float*)d_in[21];
  const float* o1w = (const float*)d_in[22];
  const float* o1b = (const float*)d_in[23];
  const float* o2w = (const float*)d_in[24];
  const float* o2b = (const float*)d_in[25];
  const float* gate = (const float*)d_in[26];
  float* out = (float*)d_out;
  float* ws = (float*)d_ws;

  // workspace layout (f32 slots) — total 14385280 slots = 57.5 MB
  u16*   vb16   = (u16*)ws;                        // bf16 v, item-major [(b,n,h)][yx][16] : 4718592 fl
  float* vf32n  = ws + 4718592;                    // f32 v of nearest n [(b,h)][yx][16]   : 2359296
  float* qbuf   = ws + 7077888;                    // q item-major [(b,h)][yx][16]          : 2359296
  float* netb   = ws + 9437184;                    // net item-major [bh][yx][16]           : 2359296
  float* dwbuf  = ws + 11796480;                   // dw mid planar [b][c][yx]              : 2359296 ; reused as outattn16
  u16*   oat16  = (u16*)dwbuf;                     // outattn bf16 [item][16]               : 2359296 u16
  float* entbf  = ws + 14155776;                   // per-head entropy                      :  147456
  float* tbbuf  = ws + 14303232;                   // time bias                             :      64
  float* wtbuf  = ws + 14303360;                   // 5 transposed weights                  :   81920
  if (ws_size < 14385280ull * 4ull) return;

  float* wt_o1 = wtbuf + 49152;
  float* wt_o2 = wtbuf + 65536;

  dim3 blk(256,1,1);
  // 0. transpose weights
  prep_k<<<dim3(64,5,1), blk, 0, stream>>>(qw, vw, pww, o1w, o2w, wtbuf);
  // 1. depthwise 7x7 + gelu -> planar dwbuf
  dw_k<<<dim3(9216,1,1), blk, 0, stream>>>(query, dww, dwb, dwbuf);
  // 2. MEGA-GEMM: q + v + pw in one launch (864 blocks)
  gemm_qvp_k<<<dim3(72,12,1), blk, 0, stream>>>(query, values, dwbuf, wtbuf,
                                                qb, vb, pwb, qbuf, netb, vf32n, vb16, relt);
  // 3. time bias
  tb_k<<<dim3(1,1,1), dim3(64,1,1), 0, stream>>>(time_enc, tw, tb, tbbuf);
  // 4. FUSED (r9 structure) -> oat16 (overwrites dwbuf, its consumers are done)
  fused_k<<<dim3(576,1,1), blk, 0, stream>>>(qbuf, vf32n, vb16, netb, relt,
                                             wih, whh, bih, bhh, offw, offb, aw, ab,
                                             tbbuf, oat16, entbf);
  // 5. entropy mean / confidence -> d_out tail (f32)
  ent_k<<<dim3(72,1,1), blk, 0, stream>>>(entbf, out);
  // 6. fused o1(gelu)->o2(gate), mid in LDS -> f32 d_out
  o1o2_k<<<dim3(72,2,1), blk, 0, stream>>>(oat16, wt_o1, o1b, wt_o2, o2b, gate, out);
}